// Round 11
// baseline (32.544 us; speedup 1.0000x reference)
//
#include <hip/hip_runtime.h>

#define NQ 12

typedef _Float16 hf2 __attribute__((ext_vector_type(2)));

#if defined(__has_builtin)
#if __has_builtin(__builtin_amdgcn_fdot2)
#define FDOT2(a,b,c) __builtin_amdgcn_fdot2((a),(b),(c),false)
#endif
#endif
#ifndef FDOT2
__device__ __forceinline__ float fdot2_sw(hf2 a, hf2 b, float c){
    return c + (float)a.x*(float)b.x + (float)a.y*(float)b.y;
}
#define FDOT2(a,b,c) fdot2_sw((a),(b),(c))
#endif

struct C2 { float r, i; };
__device__ __forceinline__ C2 cmul(C2 a, C2 b){ return C2{a.r*b.r - a.i*b.i, a.r*b.i + a.i*b.r}; }
__device__ __forceinline__ C2 cadd(C2 a, C2 b){ return C2{a.r + b.r, a.i + b.i}; }

struct V4 { float r0, i0, r1, i1; };

__device__ __forceinline__ unsigned pack2(float a, float b){
    union { hf2 h; unsigned u; } cv;
    cv.h.x = (_Float16)a; cv.h.y = (_Float16)b;
    return cv.u;
}
__device__ __forceinline__ hf2 unpack2(unsigned u){
    union { unsigned u; hf2 h; } cv; cv.u = u; return cv.h;
}
#define RL(v, L) ((unsigned)__builtin_amdgcn_readlane((int)(v), (L)))

// Fused per-wire unitary G = RZ(c)*RY(b)*RX(a) for weight-triple t -> 8 floats.
__device__ __forceinline__ void fused_gate(const float* __restrict__ wts, int t, float* o){
    float a = wts[3*t], bb = wts[3*t+1], c = wts[3*t+2];
    float sa, ca, sb, cb, sc, cc;
    sincosf(0.5f*a,  &sa, &ca);
    sincosf(0.5f*bb, &sb, &cb);
    sincosf(0.5f*c,  &sc, &cc);
    C2 rx00{ca,0.f}, rx01{0.f,-sa}, rx10{0.f,-sa}, rx11{ca,0.f};
    C2 ry00{cb,0.f}, ry01{-sb,0.f}, ry10{sb,0.f}, ry11{cb,0.f};
    C2 m00 = cadd(cmul(ry00,rx00), cmul(ry01,rx10));
    C2 m01 = cadd(cmul(ry00,rx01), cmul(ry01,rx11));
    C2 m10 = cadd(cmul(ry10,rx00), cmul(ry11,rx10));
    C2 m11 = cadd(cmul(ry10,rx01), cmul(ry11,rx11));
    C2 e0{cc,-sc}, e1{cc,sc};
    C2 g00 = cmul(e0,m00), g01 = cmul(e0,m01);
    C2 g10 = cmul(e1,m10), g11 = cmul(e1,m11);
    o[0]=g00.r; o[1]=g00.i; o[2]=g01.r; o[3]=g01.i;
    o[4]=g10.r; o[5]=g10.i; o[6]=g11.r; o[7]=g11.i;
}

__device__ __forceinline__ V4 loadv(const float* __restrict__ g0, int w, float xw){
    float sx, cx;
    __sincosf(0.5f * xw, &sx, &cx);
    const float* g = g0 + w*8;
    V4 v;
    v.r0 = g[0]*cx + g[2]*sx;  v.i0 = g[1]*cx + g[3]*sx;
    v.r1 = g[4]*cx + g[6]*sx;  v.i1 = g[5]*cx + g[7]*sx;
    return v;
}

__device__ __forceinline__ void cmulsel(float& ar, float& ai, const V4& v, int bit){
    float br = bit ? v.r1 : v.r0;
    float bi = bit ? v.i1 : v.i0;
    float nr = ar*br - ai*bi, ni = ar*bi + ai*br;
    ar = nr; ai = ni;
}

// Build A/B (64x64, f16 complex), 4-column-group layout:
//   part*4096 + (col>>2)*256 + row*4 + (col&3).
// Block 0 also exports layer-0 gates (96 floats).
__global__ void build_AB(const float* __restrict__ wts, unsigned* __restrict__ AB,
                         float* __restrict__ g0out){
    __shared__ float sG[192];
    const int tid = threadIdx.x;
    if (tid < 24) fused_gate(wts, tid, sG + tid*8);
    __syncthreads();
    if (blockIdx.x == 0 && tid < 96) g0out[tid] = sG[tid];
    const int idx  = blockIdx.x * 256 + tid;    // 0..8191
    const int part = idx >> 12;
    const int e    = idx & 4095;
    const int row  = e & 63;
    const int col  = e >> 6;
    const float* gb = sG + (part ? 18*8 : 12*8);
    float cr = 1.f, ci = 0.f;
    #pragma unroll
    for (int w = 0; w < 6; ++w){
        int rb = (row >> (5-w)) & 1;
        int cb = (col >> (5-w)) & 1;
        const float* g = gb + w*8 + (rb*2+cb)*2;
        float ar = g[0], ai = g[1];
        float nr = cr*ar - ci*ai, ni = cr*ai + ci*ar;
        cr = nr; ci = ni;
    }
    AB[part*4096 + (col>>2)*256 + row*4 + (col&3)] = pack2(cr, ci);
}

#define CHAIN6(v, P) \
    float P##d1 = (v) - __shfl_xor((v),32); \
    float P##d2 = P##d1 - __shfl_xor(P##d1,16); \
    float P##d3 = P##d2 - __shfl_xor(P##d2,8); \
    float P##d4 = P##d3 - __shfl_xor(P##d3,4); \
    float P##d5 = P##d4 - __shfl_xor(P##d4,2); \
    float P##R5 = P##d5 - __shfl_xor(P##d5,1); \
    float P##R0 = P##d1; P##R0 += __shfl_xor(P##R0,16); P##R0 += __shfl_xor(P##R0,8); \
        P##R0 += __shfl_xor(P##R0,4); P##R0 += __shfl_xor(P##R0,2); P##R0 += __shfl_xor(P##R0,1); \
    float P##R1 = P##d2; P##R1 += __shfl_xor(P##R1,8); P##R1 += __shfl_xor(P##R1,4); \
        P##R1 += __shfl_xor(P##R1,2); P##R1 += __shfl_xor(P##R1,1); \
    float P##R2 = P##d3; P##R2 += __shfl_xor(P##R2,4); P##R2 += __shfl_xor(P##R2,2); P##R2 += __shfl_xor(P##R2,1); \
    float P##R3 = P##d4; P##R3 += __shfl_xor(P##R3,2); P##R3 += __shfl_xor(P##R3,1); \
    float P##R4 = P##d5; P##R4 += __shfl_xor(P##R4,1);

#define PLAIN6(v, name) \
    float name = (v); name += __shfl_xor(name,32); name += __shfl_xor(name,16); \
    name += __shfl_xor(name,8); name += __shfl_xor(name,4); name += __shfl_xor(name,2); name += __shfl_xor(name,1);

#define SBFLY(v, name) \
    float name = (v) - __shfl_xor((v),32); \
    name = name - __shfl_xor(name,16); \
    name = name - __shfl_xor(name,8); \
    name = name - __shfl_xor(name,4); \
    name = name - __shfl_xor(name,2); \
    name = name - __shfl_xor(name,1);

struct Prep { unsigned hx, hy, bx, by; V4 v6; };

// Per-element prep: v_w, gray products -> packed H2/base registers. Scoped so
// the 12 V4 temporaries die here (keeps VGPR pressure manageable at E=2).
__device__ __forceinline__ Prep prep_elem(const float* __restrict__ x,
                                          const float* __restrict__ g0,
                                          int b, int lane){
    const float4* xv = reinterpret_cast<const float4*>(x + (size_t)b * NQ);
    float4 xa = xv[0], xb = xv[1], xc = xv[2];
    Prep P;
    {
        V4 v0  = loadv(g0, 0,  xa.x);
        V4 v1  = loadv(g0, 1,  xa.y);
        V4 v2  = loadv(g0, 2,  xa.z);
        V4 v3  = loadv(g0, 3,  xa.w);
        V4 v4  = loadv(g0, 4,  xb.x);
        V4 v5  = loadv(g0, 5,  xb.y);
        const int g0b = (lane>>5)&1;
        const int g1b = ((lane>>4)^(lane>>5))&1;
        const int g2b = ((lane>>3)^(lane>>4))&1;
        const int g3b = ((lane>>2)^(lane>>3))&1;
        const int g4b = ((lane>>1)^(lane>>2))&1;
        const int g5b = ( lane    ^(lane>>1))&1;
        float hr_ = g0b ? v0.r1 : v0.r0;
        float hi_ = g0b ? v0.i1 : v0.i0;
        cmulsel(hr_, hi_, v1, g1b);
        cmulsel(hr_, hi_, v2, g2b);
        cmulsel(hr_, hi_, v3, g3b);
        cmulsel(hr_, hi_, v4, g4b);
        cmulsel(hr_, hi_, v5, g5b);
        P.hx = pack2(hr_, -hi_);
        P.hy = pack2(hi_, hr_);
    }
    {
        V4 v7  = loadv(g0, 7,  xb.w);
        V4 v8  = loadv(g0, 8,  xc.x);
        V4 v9  = loadv(g0, 9,  xc.y);
        V4 v10 = loadv(g0, 10, xc.z);
        V4 v11 = loadv(g0, 11, xc.w);
        const int b1 = ((lane>>4)^(lane>>5))&1;
        const int b2 = ((lane>>3)^(lane>>4))&1;
        const int b3 = ((lane>>2)^(lane>>3))&1;
        const int b4 = ((lane>>1)^(lane>>2))&1;
        const int b5 = ( lane    ^(lane>>1))&1;
        float br_ = b1 ? v7.r1 : v7.r0;
        float bi_ = b1 ? v7.i1 : v7.i0;
        cmulsel(br_, bi_, v8,  b2);
        cmulsel(br_, bi_, v9,  b3);
        cmulsel(br_, bi_, v10, b4);
        cmulsel(br_, bi_, v11, b5);
        P.bx = pack2(br_, -bi_);
        P.by = pack2(bi_, br_);
    }
    P.v6 = loadv(g0, 6, xb.z);
    return P;
}

// E=2: each wave evaluates TWO batch elements, sharing every A/B ds_read_b128
// between them (matrix reads are batch-invariant -> amortize the DS pipe,
// which is the measured bottleneck).
__global__ __launch_bounds__(512)
void qsim(const float* __restrict__ x, const float* __restrict__ g0,
          const unsigned* __restrict__ AB, float* __restrict__ out, int B){
    __shared__ __align__(16) unsigned lAB[8192];   // 32 KB

    const int tid = threadIdx.x;
    {
        const uint4* src = reinterpret_cast<const uint4*>(AB);
        uint4* dst = reinterpret_cast<uint4*>(lAB);
        #pragma unroll
        for (int k = 0; k < 4; ++k) dst[tid + k*512] = src[tid + k*512];
    }
    __syncthreads();

    const int lane = tid & 63;
    const int wid  = tid >> 6;
    const int e0 = blockIdx.x * 16 + wid * 2;      // this wave: elements e0, e0+1
    if (e0 >= B) return;

    Prep pA = prep_elem(x, g0, e0,   lane);
    Prep pB = prep_elem(x, g0, e0+1, lane);

    // u matvec for both elements; one row read serves both.
    float Au0r=0.f,Au0i=0.f,Au1r=0.f,Au1i=0.f;
    float Bu0r=0.f,Bu0i=0.f,Bu1r=0.f,Bu1i=0.f;
    #pragma unroll
    for (int q = 0; q < 16; ++q){
        uint4 av = *reinterpret_cast<const uint4*>(&lAB[q*256 + lane*4]);
        hf2 a0 = unpack2(av.x), a1 = unpack2(av.y), a2 = unpack2(av.z), a3 = unpack2(av.w);
        Au0r = FDOT2(a0, unpack2(RL(pA.hx, 4*q+0)), Au0r);
        Au0i = FDOT2(a0, unpack2(RL(pA.hy, 4*q+0)), Au0i);
        Au1r = FDOT2(a1, unpack2(RL(pA.hx, 4*q+1)), Au1r);
        Au1i = FDOT2(a1, unpack2(RL(pA.hy, 4*q+1)), Au1i);
        Au0r = FDOT2(a2, unpack2(RL(pA.hx, 4*q+2)), Au0r);
        Au0i = FDOT2(a2, unpack2(RL(pA.hy, 4*q+2)), Au0i);
        Au1r = FDOT2(a3, unpack2(RL(pA.hx, 4*q+3)), Au1r);
        Au1i = FDOT2(a3, unpack2(RL(pA.hy, 4*q+3)), Au1i);
        Bu0r = FDOT2(a0, unpack2(RL(pB.hx, 4*q+0)), Bu0r);
        Bu0i = FDOT2(a0, unpack2(RL(pB.hy, 4*q+0)), Bu0i);
        Bu1r = FDOT2(a1, unpack2(RL(pB.hx, 4*q+1)), Bu1r);
        Bu1i = FDOT2(a1, unpack2(RL(pB.hy, 4*q+1)), Bu1i);
        Bu0r = FDOT2(a2, unpack2(RL(pB.hx, 4*q+2)), Bu0r);
        Bu0i = FDOT2(a2, unpack2(RL(pB.hy, 4*q+2)), Bu0i);
        Bu1r = FDOT2(a3, unpack2(RL(pB.hx, 4*q+3)), Bu1r);
        Bu1i = FDOT2(a3, unpack2(RL(pB.hy, 4*q+3)), Bu1i);
    }

    // w matvec halves for both elements.
    float AP0r=0.f,AP0i=0.f,AP1r=0.f,AP1i=0.f;
    float BP0r=0.f,BP0i=0.f,BP1r=0.f,BP1i=0.f;
    #pragma unroll
    for (int q = 0; q < 8; ++q){
        uint4 bv = *reinterpret_cast<const uint4*>(&lAB[4096 + q*256 + lane*4]);
        hf2 e0v = unpack2(bv.x), e1v = unpack2(bv.y), e2v = unpack2(bv.z), e3v = unpack2(bv.w);
        AP0r = FDOT2(e0v, unpack2(RL(pA.bx, 4*q+0)), AP0r);
        AP0i = FDOT2(e0v, unpack2(RL(pA.by, 4*q+0)), AP0i);
        AP0r = FDOT2(e1v, unpack2(RL(pA.bx, 4*q+1)), AP0r);
        AP0i = FDOT2(e1v, unpack2(RL(pA.by, 4*q+1)), AP0i);
        AP0r = FDOT2(e2v, unpack2(RL(pA.bx, 4*q+2)), AP0r);
        AP0i = FDOT2(e2v, unpack2(RL(pA.by, 4*q+2)), AP0i);
        AP0r = FDOT2(e3v, unpack2(RL(pA.bx, 4*q+3)), AP0r);
        AP0i = FDOT2(e3v, unpack2(RL(pA.by, 4*q+3)), AP0i);
        BP0r = FDOT2(e0v, unpack2(RL(pB.bx, 4*q+0)), BP0r);
        BP0i = FDOT2(e0v, unpack2(RL(pB.by, 4*q+0)), BP0i);
        BP0r = FDOT2(e1v, unpack2(RL(pB.bx, 4*q+1)), BP0r);
        BP0i = FDOT2(e1v, unpack2(RL(pB.by, 4*q+1)), BP0i);
        BP0r = FDOT2(e2v, unpack2(RL(pB.bx, 4*q+2)), BP0r);
        BP0i = FDOT2(e2v, unpack2(RL(pB.by, 4*q+2)), BP0i);
        BP0r = FDOT2(e3v, unpack2(RL(pB.bx, 4*q+3)), BP0r);
        BP0i = FDOT2(e3v, unpack2(RL(pB.by, 4*q+3)), BP0i);
    }
    #pragma unroll
    for (int q = 8; q < 16; ++q){
        uint4 bv = *reinterpret_cast<const uint4*>(&lAB[4096 + q*256 + lane*4]);
        hf2 e0v = unpack2(bv.x), e1v = unpack2(bv.y), e2v = unpack2(bv.z), e3v = unpack2(bv.w);
        AP1r = FDOT2(e0v, unpack2(RL(pA.bx, 4*q+0)), AP1r);
        AP1i = FDOT2(e0v, unpack2(RL(pA.by, 4*q+0)), AP1i);
        AP1r = FDOT2(e1v, unpack2(RL(pA.bx, 4*q+1)), AP1r);
        AP1i = FDOT2(e1v, unpack2(RL(pA.by, 4*q+1)), AP1i);
        AP1r = FDOT2(e2v, unpack2(RL(pA.bx, 4*q+2)), AP1r);
        AP1i = FDOT2(e2v, unpack2(RL(pA.by, 4*q+2)), AP1i);
        AP1r = FDOT2(e3v, unpack2(RL(pA.bx, 4*q+3)), AP1r);
        AP1i = FDOT2(e3v, unpack2(RL(pA.by, 4*q+3)), AP1i);
        BP1r = FDOT2(e0v, unpack2(RL(pB.bx, 4*q+0)), BP1r);
        BP1i = FDOT2(e0v, unpack2(RL(pB.by, 4*q+0)), BP1i);
        BP1r = FDOT2(e1v, unpack2(RL(pB.bx, 4*q+1)), BP1r);
        BP1i = FDOT2(e1v, unpack2(RL(pB.by, 4*q+1)), BP1i);
        BP1r = FDOT2(e2v, unpack2(RL(pB.bx, 4*q+2)), BP1r);
        BP1i = FDOT2(e2v, unpack2(RL(pB.by, 4*q+2)), BP1i);
        BP1r = FDOT2(e3v, unpack2(RL(pB.bx, 4*q+3)), BP1r);
        BP1i = FDOT2(e3v, unpack2(RL(pB.by, 4*q+3)), BP1i);
    }

    float* oA = out + (size_t)e0 * NQ;
    // ---- element A epilogue ----
    {
        V4 v6 = pA.v6;
        float w0r = (v6.r0*AP0r - v6.i0*AP0i) + (v6.r1*AP1r - v6.i1*AP1i);
        float w0i = (v6.r0*AP0i + v6.i0*AP0r) + (v6.r1*AP1i + v6.i1*AP1r);
        float w1r = (v6.r1*AP0r - v6.i1*AP0i) + (v6.r0*AP1r - v6.i0*AP1i);
        float w1i = (v6.r1*AP0i + v6.i1*AP0r) + (v6.r0*AP1i + v6.i0*AP1r);
        float a0 = Au0r*Au0r + Au0i*Au0i;
        float a1 = Au1r*Au1r + Au1i*Au1i;
        float zr = Au0r*Au1r + Au0i*Au1i;
        float zi = Au0i*Au1r - Au0r*Au1i;
        float b0 = w0r*w0r + w0i*w0i;
        float b1 = w1r*w1r + w1i*w1i;
        float yr = w0r*w1r + w0i*w1i;
        float yi = w0i*w1r - w0r*w1i;
        PLAIN6(b0, Pb0) PLAIN6(b1, Pb1) PLAIN6(yr, Pyr) PLAIN6(yi, Pyi)
        SBFLY(a0, Ta0) SBFLY(a1, Ta1) SBFLY(zr, Tzr) SBFLY(zi, Tzi)
        const float sgn = (__builtin_popcount((unsigned)lane) & 1) ? -1.f : 1.f;
        float alpha = a0*Pb0 + a1*Pb1 + 2.f*(zr*Pyr - zi*Pyi);
        float beta  = sgn*(Ta0*b0 + Ta1*b1 + 2.f*(Tzr*yr - Tzi*yi));
        CHAIN6(alpha, A_)
        CHAIN6(beta,  C_)
        if (lane == 0){
            oA[0]  = A_R0; oA[1]  = A_R1; oA[2]  = A_R2;
            oA[3]  = A_R3; oA[4]  = A_R4; oA[5]  = A_R5;
            oA[6]  = C_R0; oA[7]  = C_R1; oA[8]  = C_R2;
            oA[9]  = C_R3; oA[10] = C_R4; oA[11] = C_R5;
        }
    }
    // ---- element B epilogue ----
    {
        V4 v6 = pB.v6;
        float w0r = (v6.r0*BP0r - v6.i0*BP0i) + (v6.r1*BP1r - v6.i1*BP1i);
        float w0i = (v6.r0*BP0i + v6.i0*BP0r) + (v6.r1*BP1i + v6.i1*BP1r);
        float w1r = (v6.r1*BP0r - v6.i1*BP0i) + (v6.r0*BP1r - v6.i0*BP1i);
        float w1i = (v6.r1*BP0i + v6.i1*BP0r) + (v6.r0*BP1i + v6.i0*BP1r);
        float a0 = Bu0r*Bu0r + Bu0i*Bu0i;
        float a1 = Bu1r*Bu1r + Bu1i*Bu1i;
        float zr = Bu0r*Bu1r + Bu0i*Bu1i;
        float zi = Bu0i*Bu1r - Bu0r*Bu1i;
        float b0 = w0r*w0r + w0i*w0i;
        float b1 = w1r*w1r + w1i*w1i;
        float yr = w0r*w1r + w0i*w1i;
        float yi = w0i*w1r - w0r*w1i;
        PLAIN6(b0, Pb0) PLAIN6(b1, Pb1) PLAIN6(yr, Pyr) PLAIN6(yi, Pyi)
        SBFLY(a0, Ta0) SBFLY(a1, Ta1) SBFLY(zr, Tzr) SBFLY(zi, Tzi)
        const float sgn = (__builtin_popcount((unsigned)lane) & 1) ? -1.f : 1.f;
        float alpha = a0*Pb0 + a1*Pb1 + 2.f*(zr*Pyr - zi*Pyi);
        float beta  = sgn*(Ta0*b0 + Ta1*b1 + 2.f*(Tzr*yr - Tzi*yi));
        CHAIN6(alpha, A_)
        CHAIN6(beta,  C_)
        if (lane == 0){
            float* oB = oA + NQ;
            oB[0]  = A_R0; oB[1]  = A_R1; oB[2]  = A_R2;
            oB[3]  = A_R3; oB[4]  = A_R4; oB[5]  = A_R5;
            oB[6]  = C_R0; oB[7]  = C_R1; oB[8]  = C_R2;
            oB[9]  = C_R3; oB[10] = C_R4; oB[11] = C_R5;
        }
    }
}

extern "C" void kernel_launch(void* const* d_in, const int* in_sizes, int n_in,
                              void* d_out, int out_size, void* d_ws, size_t ws_size,
                              hipStream_t stream){
    const float* x   = (const float*)d_in[0];
    const float* wts = (const float*)d_in[1];
    float* out = (float*)d_out;
    unsigned* AB = (unsigned*)d_ws;                  // 32 KB f16 A/B
    float* g0buf = (float*)((char*)d_ws + 32768);    // 96 floats, layer-0 gates
    const int B = in_sizes[0] / NQ;

    build_AB<<<32, 256, 0, stream>>>(wts, AB, g0buf);
    qsim<<<(B + 15) / 16, 512, 0, stream>>>(x, g0buf, AB, out, B);
}

// Round 12
// 25.211 us; speedup vs baseline: 1.2909x; 1.2909x over previous
//
#include <hip/hip_runtime.h>

#define NQ 12

typedef _Float16 hf2 __attribute__((ext_vector_type(2)));

#if defined(__has_builtin)
#if __has_builtin(__builtin_amdgcn_fdot2)
#define FDOT2(a,b,c) __builtin_amdgcn_fdot2((a),(b),(c),false)
#endif
#endif
#ifndef FDOT2
__device__ __forceinline__ float fdot2_sw(hf2 a, hf2 b, float c){
    return c + (float)a.x*(float)b.x + (float)a.y*(float)b.y;
}
#define FDOT2(a,b,c) fdot2_sw((a),(b),(c))
#endif

struct C2 { float r, i; };
__device__ __forceinline__ C2 cmul(C2 a, C2 b){ return C2{a.r*b.r - a.i*b.i, a.r*b.i + a.i*b.r}; }
__device__ __forceinline__ C2 cadd(C2 a, C2 b){ return C2{a.r + b.r, a.i + b.i}; }

struct V4 { float r0, i0, r1, i1; };

__device__ __forceinline__ unsigned pack2(float a, float b){
    union { hf2 h; unsigned u; } cv;
    cv.h.x = (_Float16)a; cv.h.y = (_Float16)b;
    return cv.u;
}
__device__ __forceinline__ hf2 unpack2(unsigned u){
    union { unsigned u; hf2 h; } cv; cv.u = u; return cv.h;
}
// broadcast lane L's packed value to all lanes (SGPR result feeds v_dot2 directly)
#define RL(v, L) ((unsigned)__builtin_amdgcn_readlane((int)(v), (L)))

// Fused per-wire unitary G = RZ(c)*RY(b)*RX(a) for weight-triple t -> 8 floats.
__device__ __forceinline__ void fused_gate(const float* __restrict__ wts, int t, float* o){
    float a = wts[3*t], bb = wts[3*t+1], c = wts[3*t+2];
    float sa, ca, sb, cb, sc, cc;
    sincosf(0.5f*a,  &sa, &ca);
    sincosf(0.5f*bb, &sb, &cb);
    sincosf(0.5f*c,  &sc, &cc);
    C2 rx00{ca,0.f}, rx01{0.f,-sa}, rx10{0.f,-sa}, rx11{ca,0.f};
    C2 ry00{cb,0.f}, ry01{-sb,0.f}, ry10{sb,0.f}, ry11{cb,0.f};
    C2 m00 = cadd(cmul(ry00,rx00), cmul(ry01,rx10));
    C2 m01 = cadd(cmul(ry00,rx01), cmul(ry01,rx11));
    C2 m10 = cadd(cmul(ry10,rx00), cmul(ry11,rx10));
    C2 m11 = cadd(cmul(ry10,rx01), cmul(ry11,rx11));
    C2 e0{cc,-sc}, e1{cc,sc};
    C2 g00 = cmul(e0,m00), g01 = cmul(e0,m01);
    C2 g10 = cmul(e1,m10), g11 = cmul(e1,m11);
    o[0]=g00.r; o[1]=g00.i; o[2]=g01.r; o[3]=g01.i;
    o[4]=g10.r; o[5]=g10.i; o[6]=g11.r; o[7]=g11.i;
}

// v_w = G0_w * [cos(x/2), sin(x/2)]^T ; g0 is GLOBAL with uniform address ->
// scalar loads (SMEM pipe, off the DS critical path).
__device__ __forceinline__ V4 loadv(const float* __restrict__ g0, int w, float xw){
    float sx, cx;
    __sincosf(0.5f * xw, &sx, &cx);
    const float* g = g0 + w*8;
    V4 v;
    v.r0 = g[0]*cx + g[2]*sx;  v.i0 = g[1]*cx + g[3]*sx;
    v.r1 = g[4]*cx + g[6]*sx;  v.i1 = g[5]*cx + g[7]*sx;
    return v;
}

__device__ __forceinline__ void cmulsel(float& ar, float& ai, const V4& v, int bit){
    float br = bit ? v.r1 : v.r0;
    float bi = bit ? v.i1 : v.i0;
    float nr = ar*br - ai*bi, ni = ar*bi + ai*br;
    ar = nr; ai = ni;
}

// Build A/B (64x64, f16 complex), 4-column-group layout:
//   part*4096 + (col>>2)*256 + row*4 + (col&3).
// Block 0 also exports layer-0 gates (96 floats).
__global__ void build_AB(const float* __restrict__ wts, unsigned* __restrict__ AB,
                         float* __restrict__ g0out){
    __shared__ float sG[192];
    const int tid = threadIdx.x;
    if (tid < 24) fused_gate(wts, tid, sG + tid*8);
    __syncthreads();
    if (blockIdx.x == 0 && tid < 96) g0out[tid] = sG[tid];
    const int idx  = blockIdx.x * 256 + tid;    // 0..8191
    const int part = idx >> 12;
    const int e    = idx & 4095;
    const int row  = e & 63;
    const int col  = e >> 6;
    const float* gb = sG + (part ? 18*8 : 12*8);
    float cr = 1.f, ci = 0.f;
    #pragma unroll
    for (int w = 0; w < 6; ++w){
        int rb = (row >> (5-w)) & 1;
        int cb = (col >> (5-w)) & 1;
        const float* g = gb + w*8 + (rb*2+cb)*2;
        float ar = g[0], ai = g[1];
        float nr = cr*ar - ci*ai, ni = cr*ai + ci*ar;
        cr = nr; ci = ni;
    }
    AB[part*4096 + (col>>2)*256 + row*4 + (col&3)] = pack2(cr, ci);
}

#define CHAIN6(v, P) \
    float P##d1 = (v) - __shfl_xor((v),32); \
    float P##d2 = P##d1 - __shfl_xor(P##d1,16); \
    float P##d3 = P##d2 - __shfl_xor(P##d2,8); \
    float P##d4 = P##d3 - __shfl_xor(P##d3,4); \
    float P##d5 = P##d4 - __shfl_xor(P##d4,2); \
    float P##R5 = P##d5 - __shfl_xor(P##d5,1); \
    float P##R0 = P##d1; P##R0 += __shfl_xor(P##R0,16); P##R0 += __shfl_xor(P##R0,8); \
        P##R0 += __shfl_xor(P##R0,4); P##R0 += __shfl_xor(P##R0,2); P##R0 += __shfl_xor(P##R0,1); \
    float P##R1 = P##d2; P##R1 += __shfl_xor(P##R1,8); P##R1 += __shfl_xor(P##R1,4); \
        P##R1 += __shfl_xor(P##R1,2); P##R1 += __shfl_xor(P##R1,1); \
    float P##R2 = P##d3; P##R2 += __shfl_xor(P##R2,4); P##R2 += __shfl_xor(P##R2,2); P##R2 += __shfl_xor(P##R2,1); \
    float P##R3 = P##d4; P##R3 += __shfl_xor(P##R3,2); P##R3 += __shfl_xor(P##R3,1); \
    float P##R4 = P##d5; P##R4 += __shfl_xor(P##R4,1);

#define PLAIN6(v, name) \
    float name = (v); name += __shfl_xor(name,32); name += __shfl_xor(name,16); \
    name += __shfl_xor(name,8); name += __shfl_xor(name,4); name += __shfl_xor(name,2); name += __shfl_xor(name,1);

#define SBFLY(v, name) \
    float name = (v) - __shfl_xor((v),32); \
    name = name - __shfl_xor(name,16); \
    name = name - __shfl_xor(name,8); \
    name = name - __shfl_xor(name,4); \
    name = name - __shfl_xor(name,2); \
    name = name - __shfl_xor(name,1);

// Rank-2 evaluation, ONE element per wave (E=1: 32 waves/CU full occupancy is
// worth more than E=2's halved matrix reads — measured round 11 regression).
__global__ __launch_bounds__(512, 1)
void qsim(const float* __restrict__ x, const float* __restrict__ g0,
          const unsigned* __restrict__ AB, float* __restrict__ out, int B){
    __shared__ __align__(16) unsigned lAB[8192];   // 32 KB A,B f16 pairs

    const int tid = threadIdx.x;
    {   // stage A,B (L2-resident after first blocks)
        const uint4* src = reinterpret_cast<const uint4*>(AB);
        uint4* dst = reinterpret_cast<uint4*>(lAB);
        #pragma unroll
        for (int k = 0; k < 4; ++k) dst[tid + k*512] = src[tid + k*512];
    }
    __syncthreads();

    const int lane = tid & 63;
    const int wid  = tid >> 6;
    int b = blockIdx.x * 8 + wid;
    if (b >= B) return;
    // b is wave-uniform; make it provably so -> x loads become s_load (SMEM)
    b = __builtin_amdgcn_readfirstlane(b);

    const float4* xv = reinterpret_cast<const float4*>(x + (size_t)b * NQ);
    float4 xa = xv[0], xb = xv[1], xc = xv[2];

    V4 v0  = loadv(g0, 0,  xa.x);
    V4 v1  = loadv(g0, 1,  xa.y);
    V4 v2  = loadv(g0, 2,  xa.z);
    V4 v3  = loadv(g0, 3,  xa.w);
    V4 v4  = loadv(g0, 4,  xb.x);
    V4 v5  = loadv(g0, 5,  xb.y);
    V4 v6  = loadv(g0, 6,  xb.z);
    V4 v7  = loadv(g0, 7,  xb.w);
    V4 v8  = loadv(g0, 8,  xc.x);
    V4 v9  = loadv(g0, 9,  xc.y);
    V4 v10 = loadv(g0, 10, xc.z);
    V4 v11 = loadv(g0, 11, xc.w);

    // H2[j], j = lane: gray product over wires 0..5 (wire0 <-> bit5) -> packed regs
    unsigned hx, hy;
    {
        const int g0b = (lane>>5)&1;
        const int g1b = ((lane>>4)^(lane>>5))&1;
        const int g2b = ((lane>>3)^(lane>>4))&1;
        const int g3b = ((lane>>2)^(lane>>3))&1;
        const int g4b = ((lane>>1)^(lane>>2))&1;
        const int g5b = ( lane    ^(lane>>1))&1;
        float hr_ = g0b ? v0.r1 : v0.r0;
        float hi_ = g0b ? v0.i1 : v0.i0;
        cmulsel(hr_, hi_, v1, g1b);
        cmulsel(hr_, hi_, v2, g2b);
        cmulsel(hr_, hi_, v3, g3b);
        cmulsel(hr_, hi_, v4, g4b);
        cmulsel(hr_, hi_, v5, g5b);
        hx = pack2(hr_, -hi_);
        hy = pack2(hi_, hr_);
    }
    // base over wires 7..11 -> packed regs
    unsigned bx, by;
    {
        const int b1 = ((lane>>4)^(lane>>5))&1;   // wire 7
        const int b2 = ((lane>>3)^(lane>>4))&1;   // wire 8
        const int b3 = ((lane>>2)^(lane>>3))&1;   // wire 9
        const int b4 = ((lane>>1)^(lane>>2))&1;   // wire 10
        const int b5 = ( lane    ^(lane>>1))&1;   // wire 11
        float br_ = b1 ? v7.r1 : v7.r0;
        float bi_ = b1 ? v7.i1 : v7.i0;
        cmulsel(br_, bi_, v8,  b2);
        cmulsel(br_, bi_, v9,  b3);
        cmulsel(br_, bi_, v10, b4);
        cmulsel(br_, bi_, v11, b5);
        bx = pack2(br_, -bi_);
        by = pack2(bi_, br_);
    }

    // u_p[r] = sum_{j: j&1==p} A[r][j]*H2[j]; per 4 cols: 1 b128 row read +
    // 8 readlane broadcasts + 8 fdot2.
    float u0r=0.f,u0i=0.f,u1r=0.f,u1i=0.f;
    #pragma unroll
    for (int q = 0; q < 16; ++q){
        uint4 av = *reinterpret_cast<const uint4*>(&lAB[q*256 + lane*4]);
        u0r = FDOT2(unpack2(av.x), unpack2(RL(hx, 4*q+0)), u0r);
        u0i = FDOT2(unpack2(av.x), unpack2(RL(hy, 4*q+0)), u0i);
        u1r = FDOT2(unpack2(av.y), unpack2(RL(hx, 4*q+1)), u1r);
        u1i = FDOT2(unpack2(av.y), unpack2(RL(hy, 4*q+1)), u1i);
        u0r = FDOT2(unpack2(av.z), unpack2(RL(hx, 4*q+2)), u0r);
        u0i = FDOT2(unpack2(av.z), unpack2(RL(hy, 4*q+2)), u0i);
        u1r = FDOT2(unpack2(av.w), unpack2(RL(hx, 4*q+3)), u1r);
        u1i = FDOT2(unpack2(av.w), unpack2(RL(hy, 4*q+3)), u1i);
    }

    // P_h[c] = sum_{l: bit5(l)==h} B[c][l]*base[l]
    float P0r=0.f,P0i=0.f,P1r=0.f,P1i=0.f;
    #pragma unroll
    for (int q = 0; q < 8; ++q){
        uint4 bv = *reinterpret_cast<const uint4*>(&lAB[4096 + q*256 + lane*4]);
        P0r = FDOT2(unpack2(bv.x), unpack2(RL(bx, 4*q+0)), P0r);
        P0i = FDOT2(unpack2(bv.x), unpack2(RL(by, 4*q+0)), P0i);
        P0r = FDOT2(unpack2(bv.y), unpack2(RL(bx, 4*q+1)), P0r);
        P0i = FDOT2(unpack2(bv.y), unpack2(RL(by, 4*q+1)), P0i);
        P0r = FDOT2(unpack2(bv.z), unpack2(RL(bx, 4*q+2)), P0r);
        P0i = FDOT2(unpack2(bv.z), unpack2(RL(by, 4*q+2)), P0i);
        P0r = FDOT2(unpack2(bv.w), unpack2(RL(bx, 4*q+3)), P0r);
        P0i = FDOT2(unpack2(bv.w), unpack2(RL(by, 4*q+3)), P0i);
    }
    #pragma unroll
    for (int q = 8; q < 16; ++q){
        uint4 bv = *reinterpret_cast<const uint4*>(&lAB[4096 + q*256 + lane*4]);
        P1r = FDOT2(unpack2(bv.x), unpack2(RL(bx, 4*q+0)), P1r);
        P1i = FDOT2(unpack2(bv.x), unpack2(RL(by, 4*q+0)), P1i);
        P1r = FDOT2(unpack2(bv.y), unpack2(RL(bx, 4*q+1)), P1r);
        P1i = FDOT2(unpack2(bv.y), unpack2(RL(by, 4*q+1)), P1i);
        P1r = FDOT2(unpack2(bv.z), unpack2(RL(bx, 4*q+2)), P1r);
        P1i = FDOT2(unpack2(bv.z), unpack2(RL(by, 4*q+2)), P1i);
        P1r = FDOT2(unpack2(bv.w), unpack2(RL(bx, 4*q+3)), P1r);
        P1i = FDOT2(unpack2(bv.w), unpack2(RL(by, 4*q+3)), P1i);
    }
    float w0r = (v6.r0*P0r - v6.i0*P0i) + (v6.r1*P1r - v6.i1*P1i);
    float w0i = (v6.r0*P0i + v6.i0*P0r) + (v6.r1*P1i + v6.i1*P1r);
    float w1r = (v6.r1*P0r - v6.i1*P0i) + (v6.r0*P1r - v6.i0*P1i);
    float w1i = (v6.r1*P0i + v6.i1*P0r) + (v6.r0*P1i + v6.i0*P1r);

    // Row quadratics (lane = r) and col quadratics (lane = c)
    float a0 = u0r*u0r + u0i*u0i;
    float a1 = u1r*u1r + u1i*u1i;
    float zr = u0r*u1r + u0i*u1i;
    float zi = u0i*u1r - u0r*u1i;
    float b0 = w0r*w0r + w0i*w0i;
    float b1 = w1r*w1r + w1i*w1i;
    float yr = w0r*w1r + w0i*w1i;
    float yi = w0i*w1r - w0r*w1i;

    // Col plain sums (uniform) and row full-parity signed sums (uniformized)
    PLAIN6(b0, Pb0) PLAIN6(b1, Pb1) PLAIN6(yr, Pyr) PLAIN6(yi, Pyi)
    SBFLY(a0, Ta0) SBFLY(a1, Ta1) SBFLY(zr, Tzr) SBFLY(zi, Tzi)
    const float sgn = (__builtin_popcount((unsigned)lane) & 1) ? -1.f : 1.f;
    float SA0 = sgn*Ta0, SA1 = sgn*Ta1, SZr = sgn*Tzr, SZi = sgn*Tzi;

    // Per-lane bilinear combos, then one prefix-parity chain each
    float alpha = a0*Pb0 + a1*Pb1 + 2.f*(zr*Pyr - zi*Pyi);
    float beta  = SA0*b0 + SA1*b1 + 2.f*(SZr*yr - SZi*yi);
    CHAIN6(alpha, A_)
    CHAIN6(beta,  C_)

    if (lane == 0){
        float* o = out + (size_t)b * NQ;
        o[0]  = A_R0; o[1]  = A_R1; o[2]  = A_R2;
        o[3]  = A_R3; o[4]  = A_R4; o[5]  = A_R5;
        o[6]  = C_R0; o[7]  = C_R1; o[8]  = C_R2;
        o[9]  = C_R3; o[10] = C_R4; o[11] = C_R5;
    }
}

extern "C" void kernel_launch(void* const* d_in, const int* in_sizes, int n_in,
                              void* d_out, int out_size, void* d_ws, size_t ws_size,
                              hipStream_t stream){
    const float* x   = (const float*)d_in[0];
    const float* wts = (const float*)d_in[1];
    float* out = (float*)d_out;
    unsigned* AB = (unsigned*)d_ws;                       // 32 KB f16 A/B
    float* g0buf = (float*)((char*)d_ws + 32768);         // 96 floats, layer-0 gates
    const int B = in_sizes[0] / NQ;

    build_AB<<<32, 256, 0, stream>>>(wts, AB, g0buf);
    qsim<<<(B + 7) / 8, 512, 0, stream>>>(x, g0buf, AB, out, B);
}

// Round 13
// 24.264 us; speedup vs baseline: 1.3412x; 1.0390x over previous
//
#include <hip/hip_runtime.h>

#define NQ 12

struct C2 { float r, i; };
__device__ __forceinline__ C2 cmul(C2 a, C2 b){ return C2{a.r*b.r - a.i*b.i, a.r*b.i + a.i*b.r}; }
__device__ __forceinline__ C2 cadd(C2 a, C2 b){ return C2{a.r + b.r, a.i + b.i}; }

struct V4 { float r0, i0, r1, i1; };

// Fused per-wire unitary G = RZ(c)*RY(b)*RX(a) for weight-triple t -> 8 floats.
__device__ __forceinline__ void fused_gate(const float* __restrict__ wts, int t, float* o){
    float a = wts[3*t], bb = wts[3*t+1], c = wts[3*t+2];
    float sa, ca, sb, cb, sc, cc;
    sincosf(0.5f*a,  &sa, &ca);
    sincosf(0.5f*bb, &sb, &cb);
    sincosf(0.5f*c,  &sc, &cc);
    C2 rx00{ca,0.f}, rx01{0.f,-sa}, rx10{0.f,-sa}, rx11{ca,0.f};
    C2 ry00{cb,0.f}, ry01{-sb,0.f}, ry10{sb,0.f}, ry11{cb,0.f};
    C2 m00 = cadd(cmul(ry00,rx00), cmul(ry01,rx10));
    C2 m01 = cadd(cmul(ry00,rx01), cmul(ry01,rx11));
    C2 m10 = cadd(cmul(ry10,rx00), cmul(ry11,rx10));
    C2 m11 = cadd(cmul(ry10,rx01), cmul(ry11,rx11));
    C2 e0{cc,-sc}, e1{cc,sc};
    C2 g00 = cmul(e0,m00), g01 = cmul(e0,m01);
    C2 g10 = cmul(e1,m10), g11 = cmul(e1,m11);
    o[0]=g00.r; o[1]=g00.i; o[2]=g01.r; o[3]=g01.i;
    o[4]=g10.r; o[5]=g10.i; o[6]=g11.r; o[7]=g11.i;
}

// Tiny setup: all 24 fused gates -> global (192 floats). One block.
__global__ void precompute_gates(const float* __restrict__ wts, float* __restrict__ gout){
    int t = threadIdx.x;
    if (t < 24) fused_gate(wts, t, gout + t*8);
}

// v_w = G0_w * [cos(x/2), sin(x/2)]^T ; uniform address -> scalar loads.
__device__ __forceinline__ V4 loadv(const float* __restrict__ g0, int w, float xw){
    float sx, cx;
    __sincosf(0.5f * xw, &sx, &cx);
    const float* g = g0 + w*8;
    V4 v;
    v.r0 = g[0]*cx + g[2]*sx;  v.i0 = g[1]*cx + g[3]*sx;
    v.r1 = g[4]*cx + g[6]*sx;  v.i1 = g[5]*cx + g[7]*sx;
    return v;
}

__device__ __forceinline__ void cmulsel(float& ar, float& ai, const V4& v, int bit){
    float br = bit ? v.r1 : v.r0;
    float bi = bit ? v.i1 : v.i0;
    float nr = ar*br - ai*bi, ni = ar*bi + ai*br;
    ar = nr; ai = ni;
}

// Apply one single-qubit gate to a 64-dim complex vector stored one entry per
// lane: partner = lane ^ xm; new = g[bit][bit]*me + g[bit][1-bit]*partner.
__device__ __forceinline__ void gate_vec(float& xr, float& xi,
                                         float gar, float gai, float gbr, float gbi,
                                         int xm){
    float or_ = __shfl_xor(xr, xm);
    float oi_ = __shfl_xor(xi, xm);
    float nr = gar*xr - gai*xi + gbr*or_ - gbi*oi_;
    float ni = gar*xi + gai*xr + gbr*oi_ + gbi*or_;
    xr = nr; xi = ni;
}

#define CHAIN6(v, P) \
    float P##d1 = (v) - __shfl_xor((v),32); \
    float P##d2 = P##d1 - __shfl_xor(P##d1,16); \
    float P##d3 = P##d2 - __shfl_xor(P##d2,8); \
    float P##d4 = P##d3 - __shfl_xor(P##d3,4); \
    float P##d5 = P##d4 - __shfl_xor(P##d4,2); \
    float P##R5 = P##d5 - __shfl_xor(P##d5,1); \
    float P##R0 = P##d1; P##R0 += __shfl_xor(P##R0,16); P##R0 += __shfl_xor(P##R0,8); \
        P##R0 += __shfl_xor(P##R0,4); P##R0 += __shfl_xor(P##R0,2); P##R0 += __shfl_xor(P##R0,1); \
    float P##R1 = P##d2; P##R1 += __shfl_xor(P##R1,8); P##R1 += __shfl_xor(P##R1,4); \
        P##R1 += __shfl_xor(P##R1,2); P##R1 += __shfl_xor(P##R1,1); \
    float P##R2 = P##d3; P##R2 += __shfl_xor(P##R2,4); P##R2 += __shfl_xor(P##R2,2); P##R2 += __shfl_xor(P##R2,1); \
    float P##R3 = P##d4; P##R3 += __shfl_xor(P##R3,2); P##R3 += __shfl_xor(P##R3,1); \
    float P##R4 = P##d5; P##R4 += __shfl_xor(P##R4,1);

#define PLAIN6(v, name) \
    float name = (v); name += __shfl_xor(name,32); name += __shfl_xor(name,16); \
    name += __shfl_xor(name,8); name += __shfl_xor(name,4); name += __shfl_xor(name,2); name += __shfl_xor(name,1);

#define SBFLY(v, name) \
    float name = (v) - __shfl_xor((v),32); \
    name = name - __shfl_xor(name,16); \
    name = name - __shfl_xor(name,8); \
    name = name - __shfl_xor(name,4); \
    name = name - __shfl_xor(name,2); \
    name = name - __shfl_xor(name,1);

// Rank-2 evaluation, one element per wave. The layer-1 operator A (x) B is a
// TENSOR PRODUCT: instead of dense 64x64 matvecs (round 12: 48 ds_read_b128 +
// 256 readlane + 256 fdot2 + 32KB LDS + a build kernel), apply the 6 per-wire
// gates directly to the four 64-dim vectors (u0,u1 masked by j-parity; Q0,Q1
// masked by bit5): 2 shuffles + 8 FMA per vector per wire. No LDS at all;
// all fp32 (absmax improves).
__global__ __launch_bounds__(512, 1)
void qsim(const float* __restrict__ x, const float* __restrict__ G,
          float* __restrict__ out, int B){
    const int tid  = threadIdx.x;
    const int lane = tid & 63;
    const int wid  = tid >> 6;
    int b = blockIdx.x * 8 + wid;
    if (b >= B) return;
    b = __builtin_amdgcn_readfirstlane(b);

    const float* G0 = G;          // layer-0 gates (w = 0..11)
    const float* G1 = G + 96;     // layer-1 gates (w = 0..11 -> t = 12..23)

    const float4* xv = reinterpret_cast<const float4*>(x + (size_t)b * NQ);
    float4 xa = xv[0], xb = xv[1], xc = xv[2];

    V4 v0  = loadv(G0, 0,  xa.x);
    V4 v1  = loadv(G0, 1,  xa.y);
    V4 v2  = loadv(G0, 2,  xa.z);
    V4 v3  = loadv(G0, 3,  xa.w);
    V4 v4  = loadv(G0, 4,  xb.x);
    V4 v5  = loadv(G0, 5,  xb.y);
    V4 v6  = loadv(G0, 6,  xb.z);
    V4 v7  = loadv(G0, 7,  xb.w);
    V4 v8  = loadv(G0, 8,  xc.x);
    V4 v9  = loadv(G0, 9,  xc.y);
    V4 v10 = loadv(G0, 10, xc.z);
    V4 v11 = loadv(G0, 11, xc.w);

    // H2[j], j = lane: gray product over wires 0..5 (wire0 <-> bit5)
    float h2r, h2i;
    {
        const int g0b = (lane>>5)&1;
        const int g1b = ((lane>>4)^(lane>>5))&1;
        const int g2b = ((lane>>3)^(lane>>4))&1;
        const int g3b = ((lane>>2)^(lane>>3))&1;
        const int g4b = ((lane>>1)^(lane>>2))&1;
        const int g5b = ( lane    ^(lane>>1))&1;
        h2r = g0b ? v0.r1 : v0.r0;
        h2i = g0b ? v0.i1 : v0.i0;
        cmulsel(h2r, h2i, v1, g1b);
        cmulsel(h2r, h2i, v2, g2b);
        cmulsel(h2r, h2i, v3, g3b);
        cmulsel(h2r, h2i, v4, g4b);
        cmulsel(h2r, h2i, v5, g5b);
    }
    // base[l], l = lane: gray product over wires 7..11
    float bsr, bsi;
    {
        const int b1 = ((lane>>4)^(lane>>5))&1;
        const int b2 = ((lane>>3)^(lane>>4))&1;
        const int b3 = ((lane>>2)^(lane>>3))&1;
        const int b4 = ((lane>>1)^(lane>>2))&1;
        const int b5 = ( lane    ^(lane>>1))&1;
        bsr = b1 ? v7.r1 : v7.r0;
        bsi = b1 ? v7.i1 : v7.i0;
        cmulsel(bsr, bsi, v8,  b2);
        cmulsel(bsr, bsi, v9,  b3);
        cmulsel(bsr, bsi, v10, b4);
        cmulsel(bsr, bsi, v11, b5);
    }

    // Masked starting vectors.
    const int jpar = lane & 1;          // wire-5 bit of j
    const int l5   = (lane >> 5) & 1;   // wire-6 bit of l
    float u0r = jpar ? 0.f : h2r, u0i = jpar ? 0.f : h2i;
    float u1r = jpar ? h2r : 0.f, u1i = jpar ? h2i : 0.f;
    float q0r = l5   ? 0.f : bsr, q0i = l5   ? 0.f : bsi;
    float q1r = l5   ? bsr : 0.f, q1i = l5   ? bsi : 0.f;

    // A-side: gates for wires 0..5 applied to u0,u1 (bit 5-w of lane).
    #pragma unroll
    for (int w = 0; w < 6; ++w){
        const float* g = G1 + w*8;
        const int sh = 5 - w;
        const int xm = 1 << sh;
        const int bit = (lane >> sh) & 1;
        float gar = bit ? g[6] : g[0];
        float gai = bit ? g[7] : g[1];
        float gbr = bit ? g[4] : g[2];
        float gbi = bit ? g[5] : g[3];
        gate_vec(u0r, u0i, gar, gai, gbr, gbi, xm);
        gate_vec(u1r, u1i, gar, gai, gbr, gbi, xm);
    }
    // B-side: gates for wires 6..11 applied to q0,q1 (wire 6+m <-> bit 5-m).
    #pragma unroll
    for (int m = 0; m < 6; ++m){
        const float* g = G1 + (6+m)*8;
        const int sh = 5 - m;
        const int xm = 1 << sh;
        const int bit = (lane >> sh) & 1;
        float gar = bit ? g[6] : g[0];
        float gai = bit ? g[7] : g[1];
        float gbr = bit ? g[4] : g[2];
        float gbi = bit ? g[5] : g[3];
        gate_vec(q0r, q0i, gar, gai, gbr, gbi, xm);
        gate_vec(q1r, q1i, gar, gai, gbr, gbi, xm);
    }

    // w_p = v6[p]*Q0 + v6[1-p]*Q1
    float w0r = (v6.r0*q0r - v6.i0*q0i) + (v6.r1*q1r - v6.i1*q1i);
    float w0i = (v6.r0*q0i + v6.i0*q0r) + (v6.r1*q1i + v6.i1*q1r);
    float w1r = (v6.r1*q0r - v6.i1*q0i) + (v6.r0*q1r - v6.i0*q1i);
    float w1i = (v6.r1*q0i + v6.i1*q0r) + (v6.r0*q1i + v6.i0*q1r);

    // Row quadratics (lane = r) and col quadratics (lane = c)
    float a0 = u0r*u0r + u0i*u0i;
    float a1 = u1r*u1r + u1i*u1i;
    float zr = u0r*u1r + u0i*u1i;
    float zi = u0i*u1r - u0r*u1i;
    float b0 = w0r*w0r + w0i*w0i;
    float b1 = w1r*w1r + w1i*w1i;
    float yr = w0r*w1r + w0i*w1i;
    float yi = w0i*w1r - w0r*w1i;

    // Col plain sums (uniform) and row full-parity signed sums (uniformized)
    PLAIN6(b0, Pb0) PLAIN6(b1, Pb1) PLAIN6(yr, Pyr) PLAIN6(yi, Pyi)
    SBFLY(a0, Ta0) SBFLY(a1, Ta1) SBFLY(zr, Tzr) SBFLY(zi, Tzi)
    const float sgn = (__builtin_popcount((unsigned)lane) & 1) ? -1.f : 1.f;
    float SA0 = sgn*Ta0, SA1 = sgn*Ta1, SZr = sgn*Tzr, SZi = sgn*Tzi;

    // Per-lane bilinear combos, then one prefix-parity chain each
    float alpha = a0*Pb0 + a1*Pb1 + 2.f*(zr*Pyr - zi*Pyi);
    float beta  = SA0*b0 + SA1*b1 + 2.f*(SZr*yr - SZi*yi);
    CHAIN6(alpha, A_)
    CHAIN6(beta,  C_)

    if (lane == 0){
        float* o = out + (size_t)b * NQ;
        o[0]  = A_R0; o[1]  = A_R1; o[2]  = A_R2;
        o[3]  = A_R3; o[4]  = A_R4; o[5]  = A_R5;
        o[6]  = C_R0; o[7]  = C_R1; o[8]  = C_R2;
        o[9]  = C_R3; o[10] = C_R4; o[11] = C_R5;
    }
}

extern "C" void kernel_launch(void* const* d_in, const int* in_sizes, int n_in,
                              void* d_out, int out_size, void* d_ws, size_t ws_size,
                              hipStream_t stream){
    const float* x   = (const float*)d_in[0];
    const float* wts = (const float*)d_in[1];
    float* out = (float*)d_out;
    float* gbuf = (float*)d_ws;           // 24 gates * 8 floats = 768 B
    const int B = in_sizes[0] / NQ;

    precompute_gates<<<1, 64, 0, stream>>>(wts, gbuf);
    qsim<<<(B + 7) / 8, 512, 0, stream>>>(x, gbuf, out, B);
}

// Round 14
// 22.552 us; speedup vs baseline: 1.4431x; 1.0759x over previous
//
#include <hip/hip_runtime.h>

#define NQ 12

typedef _Float16 hf2 __attribute__((ext_vector_type(2)));

struct C2 { float r, i; };
__device__ __forceinline__ C2 cmul(C2 a, C2 b){ return C2{a.r*b.r - a.i*b.i, a.r*b.i + a.i*b.r}; }
__device__ __forceinline__ C2 cadd(C2 a, C2 b){ return C2{a.r + b.r, a.i + b.i}; }

__device__ __forceinline__ unsigned pk_rep(float v){
    union { _Float16 h[2]; unsigned u; } c;
    c.h[0] = (_Float16)v; c.h[1] = (_Float16)v;
    return c.u;
}
__device__ __forceinline__ hf2 u2h(unsigned u){
    union { unsigned u; hf2 h; } c; c.u = u; return c.h;
}
__device__ __forceinline__ hf2 shflx_h(hf2 v, int m){
    union { hf2 h; int i; } c; c.h = v;
    c.i = __shfl_xor(c.i, m);
    return c.h;
}
__device__ __forceinline__ float rlane_f(float v, int l){
    union { float f; int i; } c; c.f = v;
    c.i = __builtin_amdgcn_readlane(c.i, l);
    return c.f;
}

// Setup (1 wave): lanes 0..23 compute fused gates G = RZ*RY*RX.
// Lanes 0..11 -> layer-0 gates as 8 floats (per-lane loads in qsim).
// Lanes 12..23 -> layer-1 gates as 8 replicated-f16 packed words:
//   [g00r,g00i,g01r,g01i,g10r,g10i,g11r,g11i] each as (h,h).
__global__ void precompute_gates(const float* __restrict__ wts,
                                 float* __restrict__ g0out,
                                 unsigned* __restrict__ g1pk){
    int t = threadIdx.x;
    if (t >= 24) return;
    float a = wts[3*t], bb = wts[3*t+1], c = wts[3*t+2];
    float sa, ca, sb, cb, sc, cc;
    sincosf(0.5f*a,  &sa, &ca);
    sincosf(0.5f*bb, &sb, &cb);
    sincosf(0.5f*c,  &sc, &cc);
    C2 rx00{ca,0.f}, rx01{0.f,-sa}, rx10{0.f,-sa}, rx11{ca,0.f};
    C2 ry00{cb,0.f}, ry01{-sb,0.f}, ry10{sb,0.f}, ry11{cb,0.f};
    C2 m00 = cadd(cmul(ry00,rx00), cmul(ry01,rx10));
    C2 m01 = cadd(cmul(ry00,rx01), cmul(ry01,rx11));
    C2 m10 = cadd(cmul(ry10,rx00), cmul(ry11,rx10));
    C2 m11 = cadd(cmul(ry10,rx01), cmul(ry11,rx11));
    C2 e0{cc,-sc}, e1{cc,sc};
    C2 g00 = cmul(e0,m00), g01 = cmul(e0,m01);
    C2 g10 = cmul(e1,m10), g11 = cmul(e1,m11);
    if (t < 12){
        float* o = g0out + t*8;
        o[0]=g00.r; o[1]=g00.i; o[2]=g01.r; o[3]=g01.i;
        o[4]=g10.r; o[5]=g10.i; o[6]=g11.r; o[7]=g11.i;
    } else {
        unsigned* o = g1pk + (t-12)*8;
        o[0]=pk_rep(g00.r); o[1]=pk_rep(g00.i);
        o[2]=pk_rep(g01.r); o[3]=pk_rep(g01.i);
        o[4]=pk_rep(g10.r); o[5]=pk_rep(g10.i);
        o[6]=pk_rep(g11.r); o[7]=pk_rep(g11.i);
    }
}

// One f16-packed gate stage on a vector-pair (two masked vectors packed
// componentwise): 2 shuffles + 8 v_pk_fma_f16 (2x f32 FLOP rate).
__device__ __forceinline__ void gate_pk(hf2& Ur, hf2& Ui,
                                        hf2 gar, hf2 gai, hf2 gbr, hf2 gbi,
                                        int xm){
    hf2 Or = shflx_h(Ur, xm);
    hf2 Oi = shflx_h(Ui, xm);
    hf2 nr = gar*Ur - gai*Ui + gbr*Or - gbi*Oi;
    hf2 ni = gar*Ui + gai*Ur + gbr*Oi + gbi*Or;
    Ur = nr; Ui = ni;
}

#define CHAIN6(v, P) \
    float P##d1 = (v) - __shfl_xor((v),32); \
    float P##d2 = P##d1 - __shfl_xor(P##d1,16); \
    float P##d3 = P##d2 - __shfl_xor(P##d2,8); \
    float P##d4 = P##d3 - __shfl_xor(P##d3,4); \
    float P##d5 = P##d4 - __shfl_xor(P##d4,2); \
    float P##R5 = P##d5 - __shfl_xor(P##d5,1); \
    float P##R0 = P##d1; P##R0 += __shfl_xor(P##R0,16); P##R0 += __shfl_xor(P##R0,8); \
        P##R0 += __shfl_xor(P##R0,4); P##R0 += __shfl_xor(P##R0,2); P##R0 += __shfl_xor(P##R0,1); \
    float P##R1 = P##d2; P##R1 += __shfl_xor(P##R1,8); P##R1 += __shfl_xor(P##R1,4); \
        P##R1 += __shfl_xor(P##R1,2); P##R1 += __shfl_xor(P##R1,1); \
    float P##R2 = P##d3; P##R2 += __shfl_xor(P##R2,4); P##R2 += __shfl_xor(P##R2,2); P##R2 += __shfl_xor(P##R2,1); \
    float P##R3 = P##d4; P##R3 += __shfl_xor(P##R3,2); P##R3 += __shfl_xor(P##R3,1); \
    float P##R4 = P##d5; P##R4 += __shfl_xor(P##R4,1);

#define PLAIN6(v, name) \
    float name = (v); name += __shfl_xor(name,32); name += __shfl_xor(name,16); \
    name += __shfl_xor(name,8); name += __shfl_xor(name,4); name += __shfl_xor(name,2); name += __shfl_xor(name,1);

#define SBFLY(v, name) \
    float name = (v) - __shfl_xor((v),32); \
    name = name - __shfl_xor(name,16); \
    name = name - __shfl_xor(name,8); \
    name = name - __shfl_xor(name,4); \
    name = name - __shfl_xor(name,2); \
    name = name - __shfl_xor(name,1);

// Rank-2 evaluation, one element per wave, VALU-optimized:
//  - per-wire v_w prep DISTRIBUTED across lanes 0..11 (was 64x redundant
//    wave-uniform work incl. 12 sincos), redistributed into register V
//    (lane 4w+c = component c of v_w) via 4 bpermutes; gray products fetch
//    (vr,vi) with __shfl(V, 4w+2bit) — sources independent, hoistable.
//  - the four 64-dim gate cascades run in PACKED f16 (u0,u1) / (q0,q1)
//    componentwise: v_pk_fma_f16 at 2x f32 rate, half the shuffles.
__global__ __launch_bounds__(512, 1)
void qsim(const float* __restrict__ x, const float* __restrict__ G0,
          const unsigned* __restrict__ G1PK, float* __restrict__ out, int B){
    const int tid  = threadIdx.x;
    const int lane = tid & 63;
    const int wid  = tid >> 6;
    int b = blockIdx.x * 8 + wid;
    if (b >= B) return;
    b = __builtin_amdgcn_readfirstlane(b);

    // ---- distributed per-wire prep: lane w computes v_w ----
    const int wl = (lane < 12) ? lane : 0;
    float xw = x[(size_t)b * NQ + wl];
    float sx, cx;
    __sincosf(0.5f * xw, &sx, &cx);
    const float4* gme = reinterpret_cast<const float4*>(G0 + wl*8);
    float4 glo = gme[0], ghi = gme[1];
    float r0v = glo.x*cx + glo.z*sx;
    float i0v = glo.y*cx + glo.w*sx;
    float r1v = ghi.x*cx + ghi.z*sx;
    float i1v = ghi.y*cx + ghi.w*sx;

    // redistribute: V[lane] = component (lane&3) of wire (lane>>2)
    const int srcw = lane >> 2;
    float B0 = __shfl(r0v, srcw);
    float B1 = __shfl(i0v, srcw);
    float B2 = __shfl(r1v, srcw);
    float B3 = __shfl(i1v, srcw);
    const int comp = lane & 3;
    float V = (comp == 0) ? B0 : (comp == 1) ? B1 : (comp == 2) ? B2 : B3;

    // v6 (uniform) for the w_p combine
    float v6r0 = rlane_f(V, 24), v6i0 = rlane_f(V, 25);
    float v6r1 = rlane_f(V, 26), v6i1 = rlane_f(V, 27);

    // ---- H2[j], j = lane: gray product over wires 0..5 ----
    float h2r, h2i;
    {
        const int g0b = (lane>>5)&1;
        const int g1b = ((lane>>4)^(lane>>5))&1;
        const int g2b = ((lane>>3)^(lane>>4))&1;
        const int g3b = ((lane>>2)^(lane>>3))&1;
        const int g4b = ((lane>>1)^(lane>>2))&1;
        const int g5b = ( lane    ^(lane>>1))&1;
        int s0 = 2*g0b;
        h2r = __shfl(V, s0); h2i = __shfl(V, s0+1);
        {   int s = 4*1 + 2*g1b; float ar=__shfl(V,s), ai=__shfl(V,s+1);
            float nr=h2r*ar-h2i*ai, ni=h2r*ai+h2i*ar; h2r=nr; h2i=ni; }
        {   int s = 4*2 + 2*g2b; float ar=__shfl(V,s), ai=__shfl(V,s+1);
            float nr=h2r*ar-h2i*ai, ni=h2r*ai+h2i*ar; h2r=nr; h2i=ni; }
        {   int s = 4*3 + 2*g3b; float ar=__shfl(V,s), ai=__shfl(V,s+1);
            float nr=h2r*ar-h2i*ai, ni=h2r*ai+h2i*ar; h2r=nr; h2i=ni; }
        {   int s = 4*4 + 2*g4b; float ar=__shfl(V,s), ai=__shfl(V,s+1);
            float nr=h2r*ar-h2i*ai, ni=h2r*ai+h2i*ar; h2r=nr; h2i=ni; }
        {   int s = 4*5 + 2*g5b; float ar=__shfl(V,s), ai=__shfl(V,s+1);
            float nr=h2r*ar-h2i*ai, ni=h2r*ai+h2i*ar; h2r=nr; h2i=ni; }
    }
    // ---- base[l], l = lane: gray product over wires 7..11 ----
    float bsr, bsi;
    {
        const int b1 = ((lane>>4)^(lane>>5))&1;
        const int b2 = ((lane>>3)^(lane>>4))&1;
        const int b3 = ((lane>>2)^(lane>>3))&1;
        const int b4 = ((lane>>1)^(lane>>2))&1;
        const int b5 = ( lane    ^(lane>>1))&1;
        int s0 = 4*7 + 2*b1;
        bsr = __shfl(V, s0); bsi = __shfl(V, s0+1);
        {   int s = 4*8 + 2*b2;  float ar=__shfl(V,s), ai=__shfl(V,s+1);
            float nr=bsr*ar-bsi*ai, ni=bsr*ai+bsi*ar; bsr=nr; bsi=ni; }
        {   int s = 4*9 + 2*b3;  float ar=__shfl(V,s), ai=__shfl(V,s+1);
            float nr=bsr*ar-bsi*ai, ni=bsr*ai+bsi*ar; bsr=nr; bsi=ni; }
        {   int s = 4*10 + 2*b4; float ar=__shfl(V,s), ai=__shfl(V,s+1);
            float nr=bsr*ar-bsi*ai, ni=bsr*ai+bsi*ar; bsr=nr; bsi=ni; }
        {   int s = 4*11 + 2*b5; float ar=__shfl(V,s), ai=__shfl(V,s+1);
            float nr=bsr*ar-bsi*ai, ni=bsr*ai+bsi*ar; bsr=nr; bsi=ni; }
    }

    // ---- masked starting vector-pairs, packed f16 componentwise ----
    const int jpar = lane & 1;
    const int l5   = (lane >> 5) & 1;
    const _Float16 HZ = (_Float16)0.f;
    _Float16 h2rh = (_Float16)h2r, h2ih = (_Float16)h2i;
    _Float16 bsrh = (_Float16)bsr, bsih = (_Float16)bsi;
    hf2 Ur, Ui, Qr, Qi;
    { hf2 t0 = {h2rh, HZ}, t1 = {HZ, h2rh}; Ur = jpar ? t1 : t0; }
    { hf2 t0 = {h2ih, HZ}, t1 = {HZ, h2ih}; Ui = jpar ? t1 : t0; }
    { hf2 t0 = {bsrh, HZ}, t1 = {HZ, bsrh}; Qr = l5 ? t1 : t0; }
    { hf2 t0 = {bsih, HZ}, t1 = {HZ, bsih}; Qi = l5 ? t1 : t0; }

    // ---- A-side cascade: wires 0..5 on (u0,u1) ----
    #pragma unroll
    for (int w = 0; w < 6; ++w){
        const unsigned* gp = G1PK + w*8;
        const int sh = 5 - w;
        const int xm = 1 << sh;
        const int bit = (lane >> sh) & 1;
        hf2 gar = u2h(bit ? gp[6] : gp[0]);
        hf2 gai = u2h(bit ? gp[7] : gp[1]);
        hf2 gbr = u2h(bit ? gp[4] : gp[2]);
        hf2 gbi = u2h(bit ? gp[5] : gp[3]);
        gate_pk(Ur, Ui, gar, gai, gbr, gbi, xm);
    }
    // ---- B-side cascade: wires 6..11 on (q0,q1) ----
    #pragma unroll
    for (int m = 0; m < 6; ++m){
        const unsigned* gp = G1PK + (6+m)*8;
        const int sh = 5 - m;
        const int xm = 1 << sh;
        const int bit = (lane >> sh) & 1;
        hf2 gar = u2h(bit ? gp[6] : gp[0]);
        hf2 gai = u2h(bit ? gp[7] : gp[1]);
        hf2 gbr = u2h(bit ? gp[4] : gp[2]);
        hf2 gbi = u2h(bit ? gp[5] : gp[3]);
        gate_pk(Qr, Qi, gar, gai, gbr, gbi, xm);
    }

    // ---- unpack to f32 ----
    float u0r = (float)Ur.x, u1r = (float)Ur.y;
    float u0i = (float)Ui.x, u1i = (float)Ui.y;
    float q0r = (float)Qr.x, q1r = (float)Qr.y;
    float q0i = (float)Qi.x, q1i = (float)Qi.y;

    // w_p = v6[p]*Q0 + v6[1-p]*Q1
    float w0r = (v6r0*q0r - v6i0*q0i) + (v6r1*q1r - v6i1*q1i);
    float w0i = (v6r0*q0i + v6i0*q0r) + (v6r1*q1i + v6i1*q1r);
    float w1r = (v6r1*q0r - v6i1*q0i) + (v6r0*q1r - v6i0*q1i);
    float w1i = (v6r1*q0i + v6i1*q0r) + (v6r0*q1i + v6i0*q1r);

    // Row/col quadratics
    float a0 = u0r*u0r + u0i*u0i;
    float a1 = u1r*u1r + u1i*u1i;
    float zr = u0r*u1r + u0i*u1i;
    float zi = u0i*u1r - u0r*u1i;
    float b0 = w0r*w0r + w0i*w0i;
    float b1 = w1r*w1r + w1i*w1i;
    float yr = w0r*w1r + w0i*w1i;
    float yi = w0i*w1r - w0r*w1i;

    PLAIN6(b0, Pb0) PLAIN6(b1, Pb1) PLAIN6(yr, Pyr) PLAIN6(yi, Pyi)
    SBFLY(a0, Ta0) SBFLY(a1, Ta1) SBFLY(zr, Tzr) SBFLY(zi, Tzi)
    const float sgn = (__builtin_popcount((unsigned)lane) & 1) ? -1.f : 1.f;
    float SA0 = sgn*Ta0, SA1 = sgn*Ta1, SZr = sgn*Tzr, SZi = sgn*Tzi;

    float alpha = a0*Pb0 + a1*Pb1 + 2.f*(zr*Pyr - zi*Pyi);
    float beta  = SA0*b0 + SA1*b1 + 2.f*(SZr*yr - SZi*yi);
    CHAIN6(alpha, A_)
    CHAIN6(beta,  C_)

    if (lane == 0){
        float* o = out + (size_t)b * NQ;
        o[0]  = A_R0; o[1]  = A_R1; o[2]  = A_R2;
        o[3]  = A_R3; o[4]  = A_R4; o[5]  = A_R5;
        o[6]  = C_R0; o[7]  = C_R1; o[8]  = C_R2;
        o[9]  = C_R3; o[10] = C_R4; o[11] = C_R5;
    }
}

extern "C" void kernel_launch(void* const* d_in, const int* in_sizes, int n_in,
                              void* d_out, int out_size, void* d_ws, size_t ws_size,
                              hipStream_t stream){
    const float* x   = (const float*)d_in[0];
    const float* wts = (const float*)d_in[1];
    float* out = (float*)d_out;
    float* g0buf = (float*)d_ws;                          // 96 floats (layer-0)
    unsigned* g1pk = (unsigned*)((char*)d_ws + 512);      // 96 words (layer-1 f16 packed)
    const int B = in_sizes[0] / NQ;

    precompute_gates<<<1, 64, 0, stream>>>(wts, g0buf, g1pk);
    qsim<<<(B + 7) / 8, 512, 0, stream>>>(x, g0buf, g1pk, out, B);
}

// Round 16
// 20.858 us; speedup vs baseline: 1.5603x; 1.0812x over previous
//
#include <hip/hip_runtime.h>

#define NQ 12

typedef _Float16 hf2 __attribute__((ext_vector_type(2)));

struct C2 { float r, i; };
__device__ __forceinline__ C2 cmul(C2 a, C2 b){ return C2{a.r*b.r - a.i*b.i, a.r*b.i + a.i*b.r}; }
__device__ __forceinline__ C2 cadd(C2 a, C2 b){ return C2{a.r + b.r, a.i + b.i}; }

__device__ __forceinline__ unsigned pk_rep(float v){
    union { _Float16 h[2]; unsigned u; } c;
    c.h[0] = (_Float16)v; c.h[1] = (_Float16)v;
    return c.u;
}
__device__ __forceinline__ hf2 u2h(unsigned u){
    union { unsigned u; hf2 h; } c; c.u = u; return c.h;
}
__device__ __forceinline__ hf2 shflx_h(hf2 v, int m){
    union { hf2 h; int i; } c; c.h = v;
    c.i = __shfl_xor(c.i, m);
    return c.h;
}
__device__ __forceinline__ float rlane_f(float v, int l){
    union { float f; int i; } c; c.f = v;
    c.i = __builtin_amdgcn_readlane(c.i, l);
    return c.f;
}
// flip sign of v where m has bit31 set (m = 0 or 0x80000000)
__device__ __forceinline__ float xsign(float v, int m){
    union { float f; int i; } c; c.f = v;
    c.i ^= m;
    return c.f;
}

// DPP move with old=0: invalid source lanes contribute identity (0).
template<int CTRL>
__device__ __forceinline__ float dppmv(float x){
    union { float f; int i; } c; c.f = x;
    c.i = __builtin_amdgcn_update_dpp(0, c.i, CTRL, 0xf, 0xf, false);
    return c.f;
}
// rocPRIM wave64 sum: 4x row_shr prefix + row_bcast15 + row_bcast31.
// Total lands in lane 63. Pure VALU — zero DS-pipe traffic.
__device__ __forceinline__ float wsum63(float x){
    x += dppmv<0x111>(x);   // row_shr:1
    x += dppmv<0x112>(x);   // row_shr:2
    x += dppmv<0x114>(x);   // row_shr:4
    x += dppmv<0x118>(x);   // row_shr:8
    x += dppmv<0x142>(x);   // row_bcast:15
    x += dppmv<0x143>(x);   // row_bcast:31
    return x;
}

// Setup (1 wave): lanes 0..23 compute fused gates G = RZ*RY*RX.
// Lanes 0..11 -> layer-0 gates as 8 floats; lanes 12..23 -> layer-1 gates as
// 8 replicated-f16 packed words.
__global__ void precompute_gates(const float* __restrict__ wts,
                                 float* __restrict__ g0out,
                                 unsigned* __restrict__ g1pk){
    int t = threadIdx.x;
    if (t >= 24) return;
    float a = wts[3*t], bb = wts[3*t+1], c = wts[3*t+2];
    float sa, ca, sb, cb, sc, cc;
    sincosf(0.5f*a,  &sa, &ca);
    sincosf(0.5f*bb, &sb, &cb);
    sincosf(0.5f*c,  &sc, &cc);
    C2 rx00{ca,0.f}, rx01{0.f,-sa}, rx10{0.f,-sa}, rx11{ca,0.f};
    C2 ry00{cb,0.f}, ry01{-sb,0.f}, ry10{sb,0.f}, ry11{cb,0.f};
    C2 m00 = cadd(cmul(ry00,rx00), cmul(ry01,rx10));
    C2 m01 = cadd(cmul(ry00,rx01), cmul(ry01,rx11));
    C2 m10 = cadd(cmul(ry10,rx00), cmul(ry11,rx10));
    C2 m11 = cadd(cmul(ry10,rx01), cmul(ry11,rx11));
    C2 e0{cc,-sc}, e1{cc,sc};
    C2 g00 = cmul(e0,m00), g01 = cmul(e0,m01);
    C2 g10 = cmul(e1,m10), g11 = cmul(e1,m11);
    if (t < 12){
        float* o = g0out + t*8;
        o[0]=g00.r; o[1]=g00.i; o[2]=g01.r; o[3]=g01.i;
        o[4]=g10.r; o[5]=g10.i; o[6]=g11.r; o[7]=g11.i;
    } else {
        unsigned* o = g1pk + (t-12)*8;
        o[0]=pk_rep(g00.r); o[1]=pk_rep(g00.i);
        o[2]=pk_rep(g01.r); o[3]=pk_rep(g01.i);
        o[4]=pk_rep(g10.r); o[5]=pk_rep(g10.i);
        o[6]=pk_rep(g11.r); o[7]=pk_rep(g11.i);
    }
}

// One f16-packed gate stage: 2 shuffles + 8 v_pk_fma_f16.
__device__ __forceinline__ void gate_pk(hf2& Ur, hf2& Ui,
                                        hf2 gar, hf2 gai, hf2 gbr, hf2 gbi,
                                        int xm){
    hf2 Or = shflx_h(Ur, xm);
    hf2 Oi = shflx_h(Ui, xm);
    hf2 nr = gar*Ur - gai*Ui + gbr*Or - gbi*Oi;
    hf2 ni = gar*Ui + gai*Ur + gbr*Oi + gbi*Or;
    Ur = nr; Ui = ni;
}

// Rank-2 evaluation, one element per wave. Epilogue reductions via DPP VALU
// adds (DS pipe is CU-shared and was the bottleneck). ROUND-15 BUGFIX: the
// beta combo must NOT carry the per-lane sign — Ta* from wsum63 are already
// the uniform signed sums (round 14's SBFLY carried an extra (-1)^pc(lane)
// that its sgn* multiply cancelled; wsum63 does not).
__global__ __launch_bounds__(512, 1)
void qsim(const float* __restrict__ x, const float* __restrict__ G0,
          const unsigned* __restrict__ G1PK, float* __restrict__ out, int B){
    const int tid  = threadIdx.x;
    const int lane = tid & 63;
    const int wid  = tid >> 6;
    int b = blockIdx.x * 8 + wid;
    if (b >= B) return;
    b = __builtin_amdgcn_readfirstlane(b);

    // ---- distributed per-wire prep: lane w computes v_w ----
    const int wl = (lane < 12) ? lane : 0;
    float xw = x[(size_t)b * NQ + wl];
    float sx, cx;
    __sincosf(0.5f * xw, &sx, &cx);
    const float4* gme = reinterpret_cast<const float4*>(G0 + wl*8);
    float4 glo = gme[0], ghi = gme[1];
    float r0v = glo.x*cx + glo.z*sx;
    float i0v = glo.y*cx + glo.w*sx;
    float r1v = ghi.x*cx + ghi.z*sx;
    float i1v = ghi.y*cx + ghi.w*sx;

    // redistribute: V[lane] = component (lane&3) of wire (lane>>2)
    const int srcw = lane >> 2;
    float B0 = __shfl(r0v, srcw);
    float B1 = __shfl(i0v, srcw);
    float B2 = __shfl(r1v, srcw);
    float B3 = __shfl(i1v, srcw);
    const int comp = lane & 3;
    float V = (comp == 0) ? B0 : (comp == 1) ? B1 : (comp == 2) ? B2 : B3;

    // v6 (uniform) for the w_p combine
    float v6r0 = rlane_f(V, 24), v6i0 = rlane_f(V, 25);
    float v6r1 = rlane_f(V, 26), v6i1 = rlane_f(V, 27);

    // ---- H2[j], j = lane: gray product over wires 0..5 ----
    float h2r, h2i;
    {
        const int g0b = (lane>>5)&1;
        const int g1b = ((lane>>4)^(lane>>5))&1;
        const int g2b = ((lane>>3)^(lane>>4))&1;
        const int g3b = ((lane>>2)^(lane>>3))&1;
        const int g4b = ((lane>>1)^(lane>>2))&1;
        const int g5b = ( lane    ^(lane>>1))&1;
        int s0 = 2*g0b;
        h2r = __shfl(V, s0); h2i = __shfl(V, s0+1);
        {   int s = 4*1 + 2*g1b; float ar=__shfl(V,s), ai=__shfl(V,s+1);
            float nr=h2r*ar-h2i*ai, ni=h2r*ai+h2i*ar; h2r=nr; h2i=ni; }
        {   int s = 4*2 + 2*g2b; float ar=__shfl(V,s), ai=__shfl(V,s+1);
            float nr=h2r*ar-h2i*ai, ni=h2r*ai+h2i*ar; h2r=nr; h2i=ni; }
        {   int s = 4*3 + 2*g3b; float ar=__shfl(V,s), ai=__shfl(V,s+1);
            float nr=h2r*ar-h2i*ai, ni=h2r*ai+h2i*ar; h2r=nr; h2i=ni; }
        {   int s = 4*4 + 2*g4b; float ar=__shfl(V,s), ai=__shfl(V,s+1);
            float nr=h2r*ar-h2i*ai, ni=h2r*ai+h2i*ar; h2r=nr; h2i=ni; }
        {   int s = 4*5 + 2*g5b; float ar=__shfl(V,s), ai=__shfl(V,s+1);
            float nr=h2r*ar-h2i*ai, ni=h2r*ai+h2i*ar; h2r=nr; h2i=ni; }
    }
    // ---- base[l], l = lane: gray product over wires 7..11 ----
    float bsr, bsi;
    {
        const int b1 = ((lane>>4)^(lane>>5))&1;
        const int b2 = ((lane>>3)^(lane>>4))&1;
        const int b3 = ((lane>>2)^(lane>>3))&1;
        const int b4 = ((lane>>1)^(lane>>2))&1;
        const int b5 = ( lane    ^(lane>>1))&1;
        int s0 = 4*7 + 2*b1;
        bsr = __shfl(V, s0); bsi = __shfl(V, s0+1);
        {   int s = 4*8 + 2*b2;  float ar=__shfl(V,s), ai=__shfl(V,s+1);
            float nr=bsr*ar-bsi*ai, ni=bsr*ai+bsi*ar; bsr=nr; bsi=ni; }
        {   int s = 4*9 + 2*b3;  float ar=__shfl(V,s), ai=__shfl(V,s+1);
            float nr=bsr*ar-bsi*ai, ni=bsr*ai+bsi*ar; bsr=nr; bsi=ni; }
        {   int s = 4*10 + 2*b4; float ar=__shfl(V,s), ai=__shfl(V,s+1);
            float nr=bsr*ar-bsi*ai, ni=bsr*ai+bsi*ar; bsr=nr; bsi=ni; }
        {   int s = 4*11 + 2*b5; float ar=__shfl(V,s), ai=__shfl(V,s+1);
            float nr=bsr*ar-bsi*ai, ni=bsr*ai+bsi*ar; bsr=nr; bsi=ni; }
    }

    // ---- masked starting vector-pairs, packed f16 componentwise ----
    const int jpar = lane & 1;
    const int l5   = (lane >> 5) & 1;
    const _Float16 HZ = (_Float16)0.f;
    _Float16 h2rh = (_Float16)h2r, h2ih = (_Float16)h2i;
    _Float16 bsrh = (_Float16)bsr, bsih = (_Float16)bsi;
    hf2 Ur, Ui, Qr, Qi;
    { hf2 t0 = {h2rh, HZ}, t1 = {HZ, h2rh}; Ur = jpar ? t1 : t0; }
    { hf2 t0 = {h2ih, HZ}, t1 = {HZ, h2ih}; Ui = jpar ? t1 : t0; }
    { hf2 t0 = {bsrh, HZ}, t1 = {HZ, bsrh}; Qr = l5 ? t1 : t0; }
    { hf2 t0 = {bsih, HZ}, t1 = {HZ, bsih}; Qi = l5 ? t1 : t0; }

    // ---- A-side cascade: wires 0..5 on (u0,u1) ----
    #pragma unroll
    for (int w = 0; w < 6; ++w){
        const unsigned* gp = G1PK + w*8;
        const int sh = 5 - w;
        const int xm = 1 << sh;
        const int bit = (lane >> sh) & 1;
        hf2 gar = u2h(bit ? gp[6] : gp[0]);
        hf2 gai = u2h(bit ? gp[7] : gp[1]);
        hf2 gbr = u2h(bit ? gp[4] : gp[2]);
        hf2 gbi = u2h(bit ? gp[5] : gp[3]);
        gate_pk(Ur, Ui, gar, gai, gbr, gbi, xm);
    }
    // ---- B-side cascade: wires 6..11 on (q0,q1) ----
    #pragma unroll
    for (int m = 0; m < 6; ++m){
        const unsigned* gp = G1PK + (6+m)*8;
        const int sh = 5 - m;
        const int xm = 1 << sh;
        const int bit = (lane >> sh) & 1;
        hf2 gar = u2h(bit ? gp[6] : gp[0]);
        hf2 gai = u2h(bit ? gp[7] : gp[1]);
        hf2 gbr = u2h(bit ? gp[4] : gp[2]);
        hf2 gbi = u2h(bit ? gp[5] : gp[3]);
        gate_pk(Qr, Qi, gar, gai, gbr, gbi, xm);
    }

    // ---- unpack to f32 ----
    float u0r = (float)Ur.x, u1r = (float)Ur.y;
    float u0i = (float)Ui.x, u1i = (float)Ui.y;
    float q0r = (float)Qr.x, q1r = (float)Qr.y;
    float q0i = (float)Qi.x, q1i = (float)Qi.y;

    // w_p = v6[p]*Q0 + v6[1-p]*Q1
    float w0r = (v6r0*q0r - v6i0*q0i) + (v6r1*q1r - v6i1*q1i);
    float w0i = (v6r0*q0i + v6i0*q0r) + (v6r1*q1i + v6i1*q1r);
    float w1r = (v6r1*q0r - v6i1*q0i) + (v6r0*q1r - v6i0*q1i);
    float w1i = (v6r1*q0i + v6i1*q0r) + (v6r0*q1i + v6i0*q1r);

    // Row/col quadratics
    float a0 = u0r*u0r + u0i*u0i;
    float a1 = u1r*u1r + u1i*u1i;
    float zr = u0r*u1r + u0i*u1i;
    float zi = u0i*u1r - u0r*u1i;
    float b0 = w0r*w0r + w0i*w0i;
    float b1 = w1r*w1r + w1i*w1i;
    float yr = w0r*w1r + w0i*w1i;
    float yi = w0i*w1r - w0r*w1i;

    // ---- phase 1: 8 uniform reductions via DPP (0 DS ops) ----
    const int par6 = __builtin_popcount((unsigned)lane) & 1;
    const float sgnf = par6 ? -1.f : 1.f;
    float Pb0 = rlane_f(wsum63(b0), 63);
    float Pb1 = rlane_f(wsum63(b1), 63);
    float Pyr = rlane_f(wsum63(yr), 63);
    float Pyi = rlane_f(wsum63(yi), 63);
    float Ta0 = rlane_f(wsum63(sgnf*a0), 63);
    float Ta1 = rlane_f(wsum63(sgnf*a1), 63);
    float Tzr = rlane_f(wsum63(sgnf*zr), 63);
    float Tzi = rlane_f(wsum63(sgnf*zi), 63);

    // ---- phase 2: per-lane bilinear combos ----
    // Ta*/Tz* are UNIFORM signed sums; beta takes them directly (no sgnf!).
    float alpha = a0*Pb0 + a1*Pb1 + 2.f*(zr*Pyr - zi*Pyi);
    float beta  = Ta0*b0 + Ta1*b1 + 2.f*(Tzr*yr - Tzi*yi);

    // ---- phase 3: 12 signed output reductions via DPP ----
    // sigma_w(lane) = parity(lane >> (5-w)) as f32 sign-xor masks
    const int m0 = ((lane>>5)&1) << 31;
    const int m1 = (__builtin_popcount((unsigned)(lane>>4)) & 1) << 31;
    const int m2 = (__builtin_popcount((unsigned)(lane>>3)) & 1) << 31;
    const int m3 = (__builtin_popcount((unsigned)(lane>>2)) & 1) << 31;
    const int m4 = (__builtin_popcount((unsigned)(lane>>1)) & 1) << 31;
    const int m5 = par6 << 31;
    float o0  = wsum63(xsign(alpha, m0));
    float o1  = wsum63(xsign(alpha, m1));
    float o2  = wsum63(xsign(alpha, m2));
    float o3  = wsum63(xsign(alpha, m3));
    float o4  = wsum63(xsign(alpha, m4));
    float o5  = wsum63(xsign(alpha, m5));
    float o6  = wsum63(xsign(beta,  m0));
    float o7  = wsum63(xsign(beta,  m1));
    float o8  = wsum63(xsign(beta,  m2));
    float o9  = wsum63(xsign(beta,  m3));
    float o10 = wsum63(xsign(beta,  m4));
    float o11 = wsum63(xsign(beta,  m5));

    if (lane == 63){
        float* o = out + (size_t)b * NQ;
        o[0] = o0;  o[1] = o1;  o[2]  = o2;  o[3]  = o3;
        o[4] = o4;  o[5] = o5;  o[6]  = o6;  o[7]  = o7;
        o[8] = o8;  o[9] = o9;  o[10] = o10; o[11] = o11;
    }
}

extern "C" void kernel_launch(void* const* d_in, const int* in_sizes, int n_in,
                              void* d_out, int out_size, void* d_ws, size_t ws_size,
                              hipStream_t stream){
    const float* x   = (const float*)d_in[0];
    const float* wts = (const float*)d_in[1];
    float* out = (float*)d_out;
    float* g0buf = (float*)d_ws;                          // 96 floats (layer-0)
    unsigned* g1pk = (unsigned*)((char*)d_ws + 512);      // 96 words (layer-1 f16 packed)
    const int B = in_sizes[0] / NQ;

    precompute_gates<<<1, 64, 0, stream>>>(wts, g0buf, g1pk);
    qsim<<<(B + 7) / 8, 512, 0, stream>>>(x, g0buf, g1pk, out, B);
}

// Round 17
// 18.326 us; speedup vs baseline: 1.7758x; 1.1382x over previous
//
#include <hip/hip_runtime.h>

#define NQ 12

typedef _Float16 hf2 __attribute__((ext_vector_type(2)));

struct C2 { float r, i; };
__device__ __forceinline__ C2 cmul(C2 a, C2 b){ return C2{a.r*b.r - a.i*b.i, a.r*b.i + a.i*b.r}; }
__device__ __forceinline__ C2 cadd(C2 a, C2 b){ return C2{a.r + b.r, a.i + b.i}; }

__device__ __forceinline__ unsigned pk_rep(float v){
    union { _Float16 h[2]; unsigned u; } c;
    c.h[0] = (_Float16)v; c.h[1] = (_Float16)v;
    return c.u;
}
__device__ __forceinline__ hf2 u2h(unsigned u){
    union { unsigned u; hf2 h; } c; c.u = u; return c.h;
}
__device__ __forceinline__ hf2 shflx_h(hf2 v, int m){
    union { hf2 h; int i; } c; c.h = v;
    c.i = __shfl_xor(c.i, m);
    return c.h;
}
__device__ __forceinline__ float rlane_f(float v, int l){
    union { float f; int i; } c; c.f = v;
    c.i = __builtin_amdgcn_readlane(c.i, l);
    return c.f;
}
__device__ __forceinline__ unsigned rlane_u(unsigned v, int l){
    return (unsigned)__builtin_amdgcn_readlane((int)v, l);
}
// flip sign of v where m has bit31 set (m = 0 or 0x80000000)
__device__ __forceinline__ float xsign(float v, int m){
    union { float f; int i; } c; c.f = v;
    c.i ^= m;
    return c.f;
}

// DPP move with old=0: invalid source lanes contribute identity (0).
template<int CTRL>
__device__ __forceinline__ float dppmv(float x){
    union { float f; int i; } c; c.f = x;
    c.i = __builtin_amdgcn_update_dpp(0, c.i, CTRL, 0xf, 0xf, false);
    return c.f;
}
// rocPRIM wave64 sum: 4x row_shr prefix + row_bcast15 + row_bcast31.
// Total lands in lane 63. Pure VALU — zero DS-pipe traffic.
__device__ __forceinline__ float wsum63(float x){
    x += dppmv<0x111>(x);   // row_shr:1
    x += dppmv<0x112>(x);   // row_shr:2
    x += dppmv<0x114>(x);   // row_shr:4
    x += dppmv<0x118>(x);   // row_shr:8
    x += dppmv<0x142>(x);   // row_bcast:15
    x += dppmv<0x143>(x);   // row_bcast:31
    return x;
}

// One f16-packed gate stage: 2 shuffles + 8 v_pk_fma_f16.
__device__ __forceinline__ void gate_pk(hf2& Ur, hf2& Ui,
                                        hf2 gar, hf2 gai, hf2 gbr, hf2 gbi,
                                        int xm){
    hf2 Or = shflx_h(Ur, xm);
    hf2 Oi = shflx_h(Ui, xm);
    hf2 nr = gar*Ur - gai*Ui + gbr*Or - gbi*Oi;
    hf2 ni = gar*Ui + gai*Ur + gbr*Oi + gbi*Or;
    Ur = nr; Ui = ni;
}

// SINGLE-KERNEL rank-2 evaluation, one element per wave.
// Each wave computes all 24 fused gates itself, one gate per lane (lanes
// 0..23): lane t holds G_t = RZ*RY*RX as 8 floats + 8 replicated-f16 words.
// Layer-0 lanes w<12 directly produce v_w (no gate table, no 2nd kernel, no
// s_load dependency); layer-1 cascade constants come from v_readlane of lane
// 12+w's packed words. Epilogue reductions are pure-VALU DPP.
__global__ __launch_bounds__(512, 1)
void qsim(const float* __restrict__ x, const float* __restrict__ wts,
          float* __restrict__ out, int B){
    const int tid  = threadIdx.x;
    const int lane = tid & 63;
    const int wid  = tid >> 6;
    int b = blockIdx.x * 8 + wid;
    if (b >= B) return;
    b = __builtin_amdgcn_readfirstlane(b);

    // ---- per-lane fused gate t = lane (lanes 0..23; others duplicate t=0) ----
    const int t = (lane < 24) ? lane : 0;
    float wa = wts[3*t], wb = wts[3*t+1], wc = wts[3*t+2];
    float sa, ca, sb, cb, sc, cc;
    __sincosf(0.5f*wa, &sa, &ca);
    __sincosf(0.5f*wb, &sb, &cb);
    __sincosf(0.5f*wc, &sc, &cc);
    float gf0, gf1, gf2, gf3, gf4, gf5, gf6, gf7;
    {
        C2 rx00{ca,0.f}, rx01{0.f,-sa}, rx10{0.f,-sa}, rx11{ca,0.f};
        C2 ry00{cb,0.f}, ry01{-sb,0.f}, ry10{sb,0.f}, ry11{cb,0.f};
        C2 m00 = cadd(cmul(ry00,rx00), cmul(ry01,rx10));
        C2 m01 = cadd(cmul(ry00,rx01), cmul(ry01,rx11));
        C2 m10 = cadd(cmul(ry10,rx00), cmul(ry11,rx10));
        C2 m11 = cadd(cmul(ry10,rx01), cmul(ry11,rx11));
        C2 e0{cc,-sc}, e1{cc,sc};
        C2 g00 = cmul(e0,m00), g01 = cmul(e0,m01);
        C2 g10 = cmul(e1,m10), g11 = cmul(e1,m11);
        gf0 = g00.r; gf1 = g00.i; gf2 = g01.r; gf3 = g01.i;
        gf4 = g10.r; gf5 = g10.i; gf6 = g11.r; gf7 = g11.i;
    }
    // replicated-f16 packed words (meaningful on lanes 12..23)
    unsigned pk0 = pk_rep(gf0), pk1 = pk_rep(gf1), pk2 = pk_rep(gf2), pk3 = pk_rep(gf3);
    unsigned pk4 = pk_rep(gf4), pk5 = pk_rep(gf5), pk6 = pk_rep(gf6), pk7 = pk_rep(gf7);

    // ---- layer-0 prep: lane w (w<12) computes v_w from its OWN gate ----
    const int wl = (lane < 12) ? lane : 0;
    float xw = x[(size_t)b * NQ + wl];
    float sx, cx;
    __sincosf(0.5f * xw, &sx, &cx);
    float r0v = gf0*cx + gf2*sx;
    float i0v = gf1*cx + gf3*sx;
    float r1v = gf4*cx + gf6*sx;
    float i1v = gf5*cx + gf7*sx;

    // redistribute: V[lane] = component (lane&3) of wire (lane>>2)
    const int srcw = lane >> 2;
    float B0 = __shfl(r0v, srcw);
    float B1 = __shfl(i0v, srcw);
    float B2 = __shfl(r1v, srcw);
    float B3 = __shfl(i1v, srcw);
    const int comp = lane & 3;
    float V = (comp == 0) ? B0 : (comp == 1) ? B1 : (comp == 2) ? B2 : B3;

    // v6 (uniform) for the w_p combine
    float v6r0 = rlane_f(V, 24), v6i0 = rlane_f(V, 25);
    float v6r1 = rlane_f(V, 26), v6i1 = rlane_f(V, 27);

    // ---- H2[j], j = lane: gray product over wires 0..5 ----
    float h2r, h2i;
    {
        const int g0b = (lane>>5)&1;
        const int g1b = ((lane>>4)^(lane>>5))&1;
        const int g2b = ((lane>>3)^(lane>>4))&1;
        const int g3b = ((lane>>2)^(lane>>3))&1;
        const int g4b = ((lane>>1)^(lane>>2))&1;
        const int g5b = ( lane    ^(lane>>1))&1;
        int s0 = 2*g0b;
        h2r = __shfl(V, s0); h2i = __shfl(V, s0+1);
        {   int s = 4*1 + 2*g1b; float ar=__shfl(V,s), ai=__shfl(V,s+1);
            float nr=h2r*ar-h2i*ai, ni=h2r*ai+h2i*ar; h2r=nr; h2i=ni; }
        {   int s = 4*2 + 2*g2b; float ar=__shfl(V,s), ai=__shfl(V,s+1);
            float nr=h2r*ar-h2i*ai, ni=h2r*ai+h2i*ar; h2r=nr; h2i=ni; }
        {   int s = 4*3 + 2*g3b; float ar=__shfl(V,s), ai=__shfl(V,s+1);
            float nr=h2r*ar-h2i*ai, ni=h2r*ai+h2i*ar; h2r=nr; h2i=ni; }
        {   int s = 4*4 + 2*g4b; float ar=__shfl(V,s), ai=__shfl(V,s+1);
            float nr=h2r*ar-h2i*ai, ni=h2r*ai+h2i*ar; h2r=nr; h2i=ni; }
        {   int s = 4*5 + 2*g5b; float ar=__shfl(V,s), ai=__shfl(V,s+1);
            float nr=h2r*ar-h2i*ai, ni=h2r*ai+h2i*ar; h2r=nr; h2i=ni; }
    }
    // ---- base[l], l = lane: gray product over wires 7..11 ----
    float bsr, bsi;
    {
        const int b1 = ((lane>>4)^(lane>>5))&1;
        const int b2 = ((lane>>3)^(lane>>4))&1;
        const int b3 = ((lane>>2)^(lane>>3))&1;
        const int b4 = ((lane>>1)^(lane>>2))&1;
        const int b5 = ( lane    ^(lane>>1))&1;
        int s0 = 4*7 + 2*b1;
        bsr = __shfl(V, s0); bsi = __shfl(V, s0+1);
        {   int s = 4*8 + 2*b2;  float ar=__shfl(V,s), ai=__shfl(V,s+1);
            float nr=bsr*ar-bsi*ai, ni=bsr*ai+bsi*ar; bsr=nr; bsi=ni; }
        {   int s = 4*9 + 2*b3;  float ar=__shfl(V,s), ai=__shfl(V,s+1);
            float nr=bsr*ar-bsi*ai, ni=bsr*ai+bsi*ar; bsr=nr; bsi=ni; }
        {   int s = 4*10 + 2*b4; float ar=__shfl(V,s), ai=__shfl(V,s+1);
            float nr=bsr*ar-bsi*ai, ni=bsr*ai+bsi*ar; bsr=nr; bsi=ni; }
        {   int s = 4*11 + 2*b5; float ar=__shfl(V,s), ai=__shfl(V,s+1);
            float nr=bsr*ar-bsi*ai, ni=bsr*ai+bsi*ar; bsr=nr; bsi=ni; }
    }

    // ---- masked starting vector-pairs, packed f16 componentwise ----
    const int jpar = lane & 1;
    const int l5   = (lane >> 5) & 1;
    const _Float16 HZ = (_Float16)0.f;
    _Float16 h2rh = (_Float16)h2r, h2ih = (_Float16)h2i;
    _Float16 bsrh = (_Float16)bsr, bsih = (_Float16)bsi;
    hf2 Ur, Ui, Qr, Qi;
    { hf2 t0 = {h2rh, HZ}, t1 = {HZ, h2rh}; Ur = jpar ? t1 : t0; }
    { hf2 t0 = {h2ih, HZ}, t1 = {HZ, h2ih}; Ui = jpar ? t1 : t0; }
    { hf2 t0 = {bsrh, HZ}, t1 = {HZ, bsrh}; Qr = l5 ? t1 : t0; }
    { hf2 t0 = {bsih, HZ}, t1 = {HZ, bsih}; Qi = l5 ? t1 : t0; }

    // ---- A-side cascade: wires 0..5 on (u0,u1); constants from lane 12+w ----
    #pragma unroll
    for (int w = 0; w < 6; ++w){
        const int L = 12 + w;
        unsigned c0 = rlane_u(pk0, L), c1 = rlane_u(pk1, L);
        unsigned c2 = rlane_u(pk2, L), c3 = rlane_u(pk3, L);
        unsigned c4 = rlane_u(pk4, L), c5 = rlane_u(pk5, L);
        unsigned c6 = rlane_u(pk6, L), c7 = rlane_u(pk7, L);
        const int sh = 5 - w;
        const int xm = 1 << sh;
        const int bit = (lane >> sh) & 1;
        hf2 gar = u2h(bit ? c6 : c0);
        hf2 gai = u2h(bit ? c7 : c1);
        hf2 gbr = u2h(bit ? c4 : c2);
        hf2 gbi = u2h(bit ? c5 : c3);
        gate_pk(Ur, Ui, gar, gai, gbr, gbi, xm);
    }
    // ---- B-side cascade: wires 6..11 on (q0,q1); constants from lane 18+m ----
    #pragma unroll
    for (int m = 0; m < 6; ++m){
        const int L = 18 + m;
        unsigned c0 = rlane_u(pk0, L), c1 = rlane_u(pk1, L);
        unsigned c2 = rlane_u(pk2, L), c3 = rlane_u(pk3, L);
        unsigned c4 = rlane_u(pk4, L), c5 = rlane_u(pk5, L);
        unsigned c6 = rlane_u(pk6, L), c7 = rlane_u(pk7, L);
        const int sh = 5 - m;
        const int xm = 1 << sh;
        const int bit = (lane >> sh) & 1;
        hf2 gar = u2h(bit ? c6 : c0);
        hf2 gai = u2h(bit ? c7 : c1);
        hf2 gbr = u2h(bit ? c4 : c2);
        hf2 gbi = u2h(bit ? c5 : c3);
        gate_pk(Qr, Qi, gar, gai, gbr, gbi, xm);
    }

    // ---- unpack to f32 ----
    float u0r = (float)Ur.x, u1r = (float)Ur.y;
    float u0i = (float)Ui.x, u1i = (float)Ui.y;
    float q0r = (float)Qr.x, q1r = (float)Qr.y;
    float q0i = (float)Qi.x, q1i = (float)Qi.y;

    // w_p = v6[p]*Q0 + v6[1-p]*Q1
    float w0r = (v6r0*q0r - v6i0*q0i) + (v6r1*q1r - v6i1*q1i);
    float w0i = (v6r0*q0i + v6i0*q0r) + (v6r1*q1i + v6i1*q1r);
    float w1r = (v6r1*q0r - v6i1*q0i) + (v6r0*q1r - v6i0*q1i);
    float w1i = (v6r1*q0i + v6i1*q0r) + (v6r0*q1i + v6i0*q1r);

    // Row/col quadratics
    float a0 = u0r*u0r + u0i*u0i;
    float a1 = u1r*u1r + u1i*u1i;
    float zr = u0r*u1r + u0i*u1i;
    float zi = u0i*u1r - u0r*u1i;
    float b0 = w0r*w0r + w0i*w0i;
    float b1 = w1r*w1r + w1i*w1i;
    float yr = w0r*w1r + w0i*w1i;
    float yi = w0i*w1r - w0r*w1i;

    // ---- phase 1: 8 uniform reductions via DPP (0 DS ops) ----
    const int par6 = __builtin_popcount((unsigned)lane) & 1;
    const float sgnf = par6 ? -1.f : 1.f;
    float Pb0 = rlane_f(wsum63(b0), 63);
    float Pb1 = rlane_f(wsum63(b1), 63);
    float Pyr = rlane_f(wsum63(yr), 63);
    float Pyi = rlane_f(wsum63(yi), 63);
    float Ta0 = rlane_f(wsum63(sgnf*a0), 63);
    float Ta1 = rlane_f(wsum63(sgnf*a1), 63);
    float Tzr = rlane_f(wsum63(sgnf*zr), 63);
    float Tzi = rlane_f(wsum63(sgnf*zi), 63);

    // ---- phase 2: per-lane bilinear combos (Ta*/Tz* uniform; no sgnf) ----
    float alpha = a0*Pb0 + a1*Pb1 + 2.f*(zr*Pyr - zi*Pyi);
    float beta  = Ta0*b0 + Ta1*b1 + 2.f*(Tzr*yr - Tzi*yi);

    // ---- phase 3: 12 signed output reductions via DPP ----
    const int m0 = ((lane>>5)&1) << 31;
    const int m1 = (__builtin_popcount((unsigned)(lane>>4)) & 1) << 31;
    const int m2 = (__builtin_popcount((unsigned)(lane>>3)) & 1) << 31;
    const int m3 = (__builtin_popcount((unsigned)(lane>>2)) & 1) << 31;
    const int m4 = (__builtin_popcount((unsigned)(lane>>1)) & 1) << 31;
    const int m5 = par6 << 31;
    float o0  = wsum63(xsign(alpha, m0));
    float o1  = wsum63(xsign(alpha, m1));
    float o2  = wsum63(xsign(alpha, m2));
    float o3  = wsum63(xsign(alpha, m3));
    float o4  = wsum63(xsign(alpha, m4));
    float o5  = wsum63(xsign(alpha, m5));
    float o6  = wsum63(xsign(beta,  m0));
    float o7  = wsum63(xsign(beta,  m1));
    float o8  = wsum63(xsign(beta,  m2));
    float o9  = wsum63(xsign(beta,  m3));
    float o10 = wsum63(xsign(beta,  m4));
    float o11 = wsum63(xsign(beta,  m5));

    if (lane == 63){
        float* o = out + (size_t)b * NQ;
        o[0] = o0;  o[1] = o1;  o[2]  = o2;  o[3]  = o3;
        o[4] = o4;  o[5] = o5;  o[6]  = o6;  o[7]  = o7;
        o[8] = o8;  o[9] = o9;  o[10] = o10; o[11] = o11;
    }
}

extern "C" void kernel_launch(void* const* d_in, const int* in_sizes, int n_in,
                              void* d_out, int out_size, void* d_ws, size_t ws_size,
                              hipStream_t stream){
    const float* x   = (const float*)d_in[0];
    const float* wts = (const float*)d_in[1];
    float* out = (float*)d_out;
    const int B = in_sizes[0] / NQ;

    qsim<<<(B + 7) / 8, 512, 0, stream>>>(x, wts, out, B);
}

// Round 18
// 18.115 us; speedup vs baseline: 1.7966x; 1.0117x over previous
//
#include <hip/hip_runtime.h>

#define NQ 12

typedef _Float16 hf2 __attribute__((ext_vector_type(2)));

struct C2 { float r, i; };
__device__ __forceinline__ C2 cmul(C2 a, C2 b){ return C2{a.r*b.r - a.i*b.i, a.r*b.i + a.i*b.r}; }
__device__ __forceinline__ C2 cadd(C2 a, C2 b){ return C2{a.r + b.r, a.i + b.i}; }

__device__ __forceinline__ unsigned pk_rep(float v){
    union { _Float16 h[2]; unsigned u; } c;
    c.h[0] = (_Float16)v; c.h[1] = (_Float16)v;
    return c.u;
}
__device__ __forceinline__ hf2 u2h(unsigned u){
    union { unsigned u; hf2 h; } c; c.u = u; return c.h;
}
__device__ __forceinline__ hf2 shflx_h(hf2 v, int m){
    union { hf2 h; int i; } c; c.h = v;
    c.i = __shfl_xor(c.i, m);
    return c.h;
}
__device__ __forceinline__ float rlane_f(float v, int l){
    union { float f; int i; } c; c.f = v;
    c.i = __builtin_amdgcn_readlane(c.i, l);
    return c.f;
}
__device__ __forceinline__ unsigned rlane_u(unsigned v, int l){
    return (unsigned)__builtin_amdgcn_readlane((int)v, l);
}
// flip sign of v where m has bit31 set (m = 0 or 0x80000000)
__device__ __forceinline__ float xsign(float v, int m){
    union { float f; int i; } c; c.f = v;
    c.i ^= m;
    return c.f;
}

// DPP move with old=0: invalid source lanes contribute identity (0).
template<int CTRL>
__device__ __forceinline__ float dppmv(float x){
    union { float f; int i; } c; c.f = x;
    c.i = __builtin_amdgcn_update_dpp(0, c.i, CTRL, 0xf, 0xf, false);
    return c.f;
}
// rocPRIM wave64 sum: 4x row_shr prefix + row_bcast15 + row_bcast31.
// Total lands in lane 63. Pure VALU — zero DS-pipe traffic.
__device__ __forceinline__ float wsum63(float x){
    x += dppmv<0x111>(x);   // row_shr:1
    x += dppmv<0x112>(x);   // row_shr:2
    x += dppmv<0x114>(x);   // row_shr:4
    x += dppmv<0x118>(x);   // row_shr:8
    x += dppmv<0x142>(x);   // row_bcast:15
    x += dppmv<0x143>(x);   // row_bcast:31
    return x;
}

// One f16-packed gate stage: 2 shuffles + 8 v_pk_fma_f16.
__device__ __forceinline__ void gate_pk(hf2& Ur, hf2& Ui,
                                        hf2 gar, hf2 gai, hf2 gbr, hf2 gbi,
                                        int xm){
    hf2 Or = shflx_h(Ur, xm);
    hf2 Oi = shflx_h(Ui, xm);
    hf2 nr = gar*Ur - gai*Ui + gbr*Or - gbi*Oi;
    hf2 ni = gar*Ui + gai*Ur + gbr*Oi + gbi*Or;
    Ur = nr; Ui = ni;
}

// SINGLE-KERNEL rank-2 evaluation, one element per wave.
// 256-thread blocks (waves are independent: no barriers, no LDS) so CU
// residency steps in 1-wave/SIMD units; __launch_bounds__(256,5) caps VGPR
// at ~102 to target >=5 waves/SIMD (512-thread blocks quantized to 2-wave
// steps and risked 4/SIMD at the compiler's free-choice VGPR count).
__global__ __launch_bounds__(256, 5)
void qsim(const float* __restrict__ x, const float* __restrict__ wts,
          float* __restrict__ out, int B){
    const int tid  = threadIdx.x;
    const int lane = tid & 63;
    const int wid  = tid >> 6;
    int b = blockIdx.x * 4 + wid;
    if (b >= B) return;
    b = __builtin_amdgcn_readfirstlane(b);

    // ---- per-lane fused gate t = lane (lanes 0..23; others duplicate t=0) ----
    const int t = (lane < 24) ? lane : 0;
    float wa = wts[3*t], wb = wts[3*t+1], wc = wts[3*t+2];
    float sa, ca, sb, cb, sc, cc;
    __sincosf(0.5f*wa, &sa, &ca);
    __sincosf(0.5f*wb, &sb, &cb);
    __sincosf(0.5f*wc, &sc, &cc);
    float gf0, gf1, gf2, gf3, gf4, gf5, gf6, gf7;
    {
        C2 rx00{ca,0.f}, rx01{0.f,-sa}, rx10{0.f,-sa}, rx11{ca,0.f};
        C2 ry00{cb,0.f}, ry01{-sb,0.f}, ry10{sb,0.f}, ry11{cb,0.f};
        C2 m00 = cadd(cmul(ry00,rx00), cmul(ry01,rx10));
        C2 m01 = cadd(cmul(ry00,rx01), cmul(ry01,rx11));
        C2 m10 = cadd(cmul(ry10,rx00), cmul(ry11,rx10));
        C2 m11 = cadd(cmul(ry10,rx01), cmul(ry11,rx11));
        C2 e0{cc,-sc}, e1{cc,sc};
        C2 g00 = cmul(e0,m00), g01 = cmul(e0,m01);
        C2 g10 = cmul(e1,m10), g11 = cmul(e1,m11);
        gf0 = g00.r; gf1 = g00.i; gf2 = g01.r; gf3 = g01.i;
        gf4 = g10.r; gf5 = g10.i; gf6 = g11.r; gf7 = g11.i;
    }
    // replicated-f16 packed words (meaningful on lanes 12..23)
    unsigned pk0 = pk_rep(gf0), pk1 = pk_rep(gf1), pk2 = pk_rep(gf2), pk3 = pk_rep(gf3);
    unsigned pk4 = pk_rep(gf4), pk5 = pk_rep(gf5), pk6 = pk_rep(gf6), pk7 = pk_rep(gf7);

    // ---- layer-0 prep: lane w (w<12) computes v_w from its OWN gate ----
    const int wl = (lane < 12) ? lane : 0;
    float xw = x[(size_t)b * NQ + wl];
    float sx, cx;
    __sincosf(0.5f * xw, &sx, &cx);
    float r0v = gf0*cx + gf2*sx;
    float i0v = gf1*cx + gf3*sx;
    float r1v = gf4*cx + gf6*sx;
    float i1v = gf5*cx + gf7*sx;

    // redistribute: V[lane] = component (lane&3) of wire (lane>>2)
    const int srcw = lane >> 2;
    float B0 = __shfl(r0v, srcw);
    float B1 = __shfl(i0v, srcw);
    float B2 = __shfl(r1v, srcw);
    float B3 = __shfl(i1v, srcw);
    const int comp = lane & 3;
    float V = (comp == 0) ? B0 : (comp == 1) ? B1 : (comp == 2) ? B2 : B3;

    // v6 (uniform) for the w_p combine
    float v6r0 = rlane_f(V, 24), v6i0 = rlane_f(V, 25);
    float v6r1 = rlane_f(V, 26), v6i1 = rlane_f(V, 27);

    // ---- H2[j], j = lane: gray product over wires 0..5 ----
    float h2r, h2i;
    {
        const int g0b = (lane>>5)&1;
        const int g1b = ((lane>>4)^(lane>>5))&1;
        const int g2b = ((lane>>3)^(lane>>4))&1;
        const int g3b = ((lane>>2)^(lane>>3))&1;
        const int g4b = ((lane>>1)^(lane>>2))&1;
        const int g5b = ( lane    ^(lane>>1))&1;
        int s0 = 2*g0b;
        h2r = __shfl(V, s0); h2i = __shfl(V, s0+1);
        {   int s = 4*1 + 2*g1b; float ar=__shfl(V,s), ai=__shfl(V,s+1);
            float nr=h2r*ar-h2i*ai, ni=h2r*ai+h2i*ar; h2r=nr; h2i=ni; }
        {   int s = 4*2 + 2*g2b; float ar=__shfl(V,s), ai=__shfl(V,s+1);
            float nr=h2r*ar-h2i*ai, ni=h2r*ai+h2i*ar; h2r=nr; h2i=ni; }
        {   int s = 4*3 + 2*g3b; float ar=__shfl(V,s), ai=__shfl(V,s+1);
            float nr=h2r*ar-h2i*ai, ni=h2r*ai+h2i*ar; h2r=nr; h2i=ni; }
        {   int s = 4*4 + 2*g4b; float ar=__shfl(V,s), ai=__shfl(V,s+1);
            float nr=h2r*ar-h2i*ai, ni=h2r*ai+h2i*ar; h2r=nr; h2i=ni; }
        {   int s = 4*5 + 2*g5b; float ar=__shfl(V,s), ai=__shfl(V,s+1);
            float nr=h2r*ar-h2i*ai, ni=h2r*ai+h2i*ar; h2r=nr; h2i=ni; }
    }
    // ---- base[l], l = lane: gray product over wires 7..11 ----
    float bsr, bsi;
    {
        const int b1 = ((lane>>4)^(lane>>5))&1;
        const int b2 = ((lane>>3)^(lane>>4))&1;
        const int b3 = ((lane>>2)^(lane>>3))&1;
        const int b4 = ((lane>>1)^(lane>>2))&1;
        const int b5 = ( lane    ^(lane>>1))&1;
        int s0 = 4*7 + 2*b1;
        bsr = __shfl(V, s0); bsi = __shfl(V, s0+1);
        {   int s = 4*8 + 2*b2;  float ar=__shfl(V,s), ai=__shfl(V,s+1);
            float nr=bsr*ar-bsi*ai, ni=bsr*ai+bsi*ar; bsr=nr; bsi=ni; }
        {   int s = 4*9 + 2*b3;  float ar=__shfl(V,s), ai=__shfl(V,s+1);
            float nr=bsr*ar-bsi*ai, ni=bsr*ai+bsi*ar; bsr=nr; bsi=ni; }
        {   int s = 4*10 + 2*b4; float ar=__shfl(V,s), ai=__shfl(V,s+1);
            float nr=bsr*ar-bsi*ai, ni=bsr*ai+bsi*ar; bsr=nr; bsi=ni; }
        {   int s = 4*11 + 2*b5; float ar=__shfl(V,s), ai=__shfl(V,s+1);
            float nr=bsr*ar-bsi*ai, ni=bsr*ai+bsi*ar; bsr=nr; bsi=ni; }
    }

    // ---- masked starting vector-pairs, packed f16 componentwise ----
    const int jpar = lane & 1;
    const int l5   = (lane >> 5) & 1;
    const _Float16 HZ = (_Float16)0.f;
    _Float16 h2rh = (_Float16)h2r, h2ih = (_Float16)h2i;
    _Float16 bsrh = (_Float16)bsr, bsih = (_Float16)bsi;
    hf2 Ur, Ui, Qr, Qi;
    { hf2 t0 = {h2rh, HZ}, t1 = {HZ, h2rh}; Ur = jpar ? t1 : t0; }
    { hf2 t0 = {h2ih, HZ}, t1 = {HZ, h2ih}; Ui = jpar ? t1 : t0; }
    { hf2 t0 = {bsrh, HZ}, t1 = {HZ, bsrh}; Qr = l5 ? t1 : t0; }
    { hf2 t0 = {bsih, HZ}, t1 = {HZ, bsih}; Qi = l5 ? t1 : t0; }

    // ---- A-side cascade: wires 0..5 on (u0,u1); constants from lane 12+w ----
    #pragma unroll
    for (int w = 0; w < 6; ++w){
        const int L = 12 + w;
        unsigned c0 = rlane_u(pk0, L), c1 = rlane_u(pk1, L);
        unsigned c2 = rlane_u(pk2, L), c3 = rlane_u(pk3, L);
        unsigned c4 = rlane_u(pk4, L), c5 = rlane_u(pk5, L);
        unsigned c6 = rlane_u(pk6, L), c7 = rlane_u(pk7, L);
        const int sh = 5 - w;
        const int xm = 1 << sh;
        const int bit = (lane >> sh) & 1;
        hf2 gar = u2h(bit ? c6 : c0);
        hf2 gai = u2h(bit ? c7 : c1);
        hf2 gbr = u2h(bit ? c4 : c2);
        hf2 gbi = u2h(bit ? c5 : c3);
        gate_pk(Ur, Ui, gar, gai, gbr, gbi, xm);
    }
    // ---- B-side cascade: wires 6..11 on (q0,q1); constants from lane 18+m ----
    #pragma unroll
    for (int m = 0; m < 6; ++m){
        const int L = 18 + m;
        unsigned c0 = rlane_u(pk0, L), c1 = rlane_u(pk1, L);
        unsigned c2 = rlane_u(pk2, L), c3 = rlane_u(pk3, L);
        unsigned c4 = rlane_u(pk4, L), c5 = rlane_u(pk5, L);
        unsigned c6 = rlane_u(pk6, L), c7 = rlane_u(pk7, L);
        const int sh = 5 - m;
        const int xm = 1 << sh;
        const int bit = (lane >> sh) & 1;
        hf2 gar = u2h(bit ? c6 : c0);
        hf2 gai = u2h(bit ? c7 : c1);
        hf2 gbr = u2h(bit ? c4 : c2);
        hf2 gbi = u2h(bit ? c5 : c3);
        gate_pk(Qr, Qi, gar, gai, gbr, gbi, xm);
    }

    // ---- unpack to f32 ----
    float u0r = (float)Ur.x, u1r = (float)Ur.y;
    float u0i = (float)Ui.x, u1i = (float)Ui.y;
    float q0r = (float)Qr.x, q1r = (float)Qr.y;
    float q0i = (float)Qi.x, q1i = (float)Qi.y;

    // w_p = v6[p]*Q0 + v6[1-p]*Q1
    float w0r = (v6r0*q0r - v6i0*q0i) + (v6r1*q1r - v6i1*q1i);
    float w0i = (v6r0*q0i + v6i0*q0r) + (v6r1*q1i + v6i1*q1r);
    float w1r = (v6r1*q0r - v6i1*q0i) + (v6r0*q1r - v6i0*q1i);
    float w1i = (v6r1*q0i + v6i1*q0r) + (v6r0*q1i + v6i0*q1r);

    // Row/col quadratics
    float a0 = u0r*u0r + u0i*u0i;
    float a1 = u1r*u1r + u1i*u1i;
    float zr = u0r*u1r + u0i*u1i;
    float zi = u0i*u1r - u0r*u1i;
    float b0 = w0r*w0r + w0i*w0i;
    float b1 = w1r*w1r + w1i*w1i;
    float yr = w0r*w1r + w0i*w1i;
    float yi = w0i*w1r - w0r*w1i;

    // ---- phase 1: 8 uniform reductions via DPP (0 DS ops) ----
    const int par6 = __builtin_popcount((unsigned)lane) & 1;
    const float sgnf = par6 ? -1.f : 1.f;
    float Pb0 = rlane_f(wsum63(b0), 63);
    float Pb1 = rlane_f(wsum63(b1), 63);
    float Pyr = rlane_f(wsum63(yr), 63);
    float Pyi = rlane_f(wsum63(yi), 63);
    float Ta0 = rlane_f(wsum63(sgnf*a0), 63);
    float Ta1 = rlane_f(wsum63(sgnf*a1), 63);
    float Tzr = rlane_f(wsum63(sgnf*zr), 63);
    float Tzi = rlane_f(wsum63(sgnf*zi), 63);

    // ---- phase 2: per-lane bilinear combos (Ta*/Tz* uniform; no sgnf) ----
    float alpha = a0*Pb0 + a1*Pb1 + 2.f*(zr*Pyr - zi*Pyi);
    float beta  = Ta0*b0 + Ta1*b1 + 2.f*(Tzr*yr - Tzi*yi);

    // ---- phase 3: 12 signed output reductions via DPP ----
    const int m0 = ((lane>>5)&1) << 31;
    const int m1 = (__builtin_popcount((unsigned)(lane>>4)) & 1) << 31;
    const int m2 = (__builtin_popcount((unsigned)(lane>>3)) & 1) << 31;
    const int m3 = (__builtin_popcount((unsigned)(lane>>2)) & 1) << 31;
    const int m4 = (__builtin_popcount((unsigned)(lane>>1)) & 1) << 31;
    const int m5 = par6 << 31;
    float o0  = wsum63(xsign(alpha, m0));
    float o1  = wsum63(xsign(alpha, m1));
    float o2  = wsum63(xsign(alpha, m2));
    float o3  = wsum63(xsign(alpha, m3));
    float o4  = wsum63(xsign(alpha, m4));
    float o5  = wsum63(xsign(alpha, m5));
    float o6  = wsum63(xsign(beta,  m0));
    float o7  = wsum63(xsign(beta,  m1));
    float o8  = wsum63(xsign(beta,  m2));
    float o9  = wsum63(xsign(beta,  m3));
    float o10 = wsum63(xsign(beta,  m4));
    float o11 = wsum63(xsign(beta,  m5));

    if (lane == 63){
        float* o = out + (size_t)b * NQ;
        o[0] = o0;  o[1] = o1;  o[2]  = o2;  o[3]  = o3;
        o[4] = o4;  o[5] = o5;  o[6]  = o6;  o[7]  = o7;
        o[8] = o8;  o[9] = o9;  o[10] = o10; o[11] = o11;
    }
}

extern "C" void kernel_launch(void* const* d_in, const int* in_sizes, int n_in,
                              void* d_out, int out_size, void* d_ws, size_t ws_size,
                              hipStream_t stream){
    const float* x   = (const float*)d_in[0];
    const float* wts = (const float*)d_in[1];
    float* out = (float*)d_out;
    const int B = in_sizes[0] / NQ;

    qsim<<<(B + 3) / 4, 256, 0, stream>>>(x, wts, out, B);
}